// Round 4
// baseline (206.292 us; speedup 1.0000x reference)
//
#include <hip/hip_runtime.h>
#include <hip/hip_bf16.h>

typedef __attribute__((ext_vector_type(8))) short short8;
typedef __attribute__((ext_vector_type(4))) float f32x4;

// ---- ws layout: p_flat (409600 f32 = 1638400 B) then bf16 weight slabs ----
// per zone (shorts): Wih [192][32] @0, Whh [192][64] @6144,
//                    W1 [64][64] @18432, W2 [64][64] @22528; stride 26624.
#define ZW 26624
#define WS_W_OFF_BYTES 1638400

__device__ __forceinline__ unsigned short f2bf(float f) {
    unsigned u = __float_as_uint(f);
    return (unsigned short)((u + 0x7FFFu + ((u >> 16) & 1u)) >> 16);  // RNE
}
__device__ __forceinline__ float sigf(float x) {
    return __builtin_amdgcn_rcpf(1.f + __builtin_amdgcn_exp2f(-1.4426950408889634f * x));
}
__device__ __forceinline__ float tanhfast(float y) {
    return 1.f - 2.f * __builtin_amdgcn_rcpf(1.f + __builtin_amdgcn_exp2f(2.8853900817779268f * y));
}

// ---------------------------------------------------------------------------
// Pre-pass: convert actor weights f32 -> bf16 fragment-ready slabs in ws.
// ---------------------------------------------------------------------------
__global__ __launch_bounds__(256)
void convert_kernel(const float* __restrict__ Wih, const float* __restrict__ Whh,
                    const float* __restrict__ W1, const float* __restrict__ W2,
                    unsigned short* __restrict__ dst)
{
    int idx = blockIdx.x * 256 + threadIdx.x;
    if (idx >= 100 * ZW) return;
    int n = idx / ZW;
    int i = idx - n * ZW;
    float v;
    if (i < 6144) {
        int row = i >> 5, k = i & 31;
        v = (k < 6) ? Wih[n * 1152 + row * 6 + k] : 0.f;
    } else if (i < 18432) {
        int j = i - 6144;
        v = Whh[n * 12288 + j];
    } else if (i < 22528) {
        int j = i - 18432;
        v = W1[n * 4096 + j];
    } else {
        int j = i - 22528;
        v = W2[n * 4096 + j];
    }
    dst[idx] = f2bf(v);
}

// ---------------------------------------------------------------------------
// Actor (MFMA bf16): grid (32,100), block 256 = 4 fully-independent waves.
// Wave w owns batches b0+w*16..+15. lane: bcol/arow = l&15, grp = l>>4.
// A-frags batched into arrays (force parallel global-load issue), biases from
// global (L2-hot dwordx4), x staged wave-locally -> NO __syncthreads at all.
// C/D: col=lane&15 (batch), row=(lane>>4)*4+reg (channel)  [m89-verified].
// ---------------------------------------------------------------------------
__global__ __launch_bounds__(256, 4)
void actor_kernel(const float* __restrict__ x, const unsigned short* __restrict__ wz,
                  const float* __restrict__ bih, const float* __restrict__ bhh,
                  const float* __restrict__ b1, const float* __restrict__ b2,
                  const float* __restrict__ W3, const float* __restrict__ b3,
                  float* __restrict__ p_flat)
{
    __shared__ char sm[20480];
    const int tid = threadIdx.x;
    const int n   = blockIdx.y;
    const int b0  = blockIdx.x * 64;
    const int w    = tid >> 6;
    const int l    = tid & 63;
    const int bcol = l & 15;
    const int grp  = l >> 4;
    const int arow = bcol;
    const int ch0  = grp * 4;
    const unsigned short* zb = wz + (size_t)n * ZW;
    char* uXw = sm + w * 512;              // [2 t][16 b][8 k] shorts
    char* Hw  = sm + 2048 + w * 2304;      // [16 b][72] shorts (h, bf16)
    char* Aw  = sm + 11264 + w * 2304;     // [16 b][72] shorts (act / m1 / m2)

    // ---- wave-local x staging (bf16, K=8 zero-padded); wave-ordered LDS ----
    for (int i = l; i < 256; i += 64) {
        int k = i & 7, b = (i >> 3) & 15, t = i >> 7;
        ((unsigned short*)uXw)[i] = (k < 6)
            ? f2bf(x[(size_t)(b0 + w * 16 + b) * 1200 + t * 600 + n * 6 + k])
            : (unsigned short)0;
    }

    const float* bihz = bih + n * 192;
    const float* bhhz = bhh + n * 192;
    const float b3v = b3[n];

    for (int t = 0; t < 2; ++t) {
        // ---- gx: batch-load 12 Wih frags, bias-init accs from global ----
        short8 af[12];
#pragma unroll
        for (int mt = 0; mt < 4; ++mt) {
            af[mt]     = *(const short8*)(zb + ((0 + mt) * 16 + arow) * 32 + grp * 8);
            af[4 + mt] = *(const short8*)(zb + ((4 + mt) * 16 + arow) * 32 + grp * 8);
            af[8 + mt] = *(const short8*)(zb + ((8 + mt) * 16 + arow) * 32 + grp * 8);
        }
        short8 bx = *(const short8*)(uXw + t * 256 + bcol * 16);
        f32x4 aR[4], aZ[4], aXN[4], aHN[4];
#pragma unroll
        for (int mt = 0; mt < 4; ++mt) {
            int ch = mt * 16 + ch0;
            aR[mt]  = *(const f32x4*)&bihz[ch]      + *(const f32x4*)&bhhz[ch];
            aZ[mt]  = *(const f32x4*)&bihz[64 + ch] + *(const f32x4*)&bhhz[64 + ch];
            aXN[mt] = *(const f32x4*)&bihz[128 + ch];
            aHN[mt] = *(const f32x4*)&bhhz[128 + ch];
        }
#pragma unroll
        for (int mt = 0; mt < 4; ++mt) {
            aR[mt]  = __builtin_amdgcn_mfma_f32_16x16x32_bf16(af[mt],     bx, aR[mt],  0, 0, 0);
            aZ[mt]  = __builtin_amdgcn_mfma_f32_16x16x32_bf16(af[4 + mt], bx, aZ[mt],  0, 0, 0);
            aXN[mt] = __builtin_amdgcn_mfma_f32_16x16x32_bf16(af[8 + mt], bx, aXN[mt], 0, 0, 0);
        }
        // ---- gh (t=1): gate-by-gate batches of 8 Whh frags ----
        if (t == 1) {
            const unsigned short* whh = zb + 6144;
            short8 bh0 = *(const short8*)(Hw + bcol * 144 + grp * 16);
            short8 bh1 = *(const short8*)(Hw + bcol * 144 + 64 + grp * 16);
            {
                short8 gf[8];
#pragma unroll
                for (int mt = 0; mt < 4; ++mt) {
                    gf[mt]     = *(const short8*)(whh + ((0 + mt) * 16 + arow) * 64 + grp * 8);
                    gf[4 + mt] = *(const short8*)(whh + ((0 + mt) * 16 + arow) * 64 + 32 + grp * 8);
                }
#pragma unroll
                for (int mt = 0; mt < 4; ++mt) {
                    aR[mt] = __builtin_amdgcn_mfma_f32_16x16x32_bf16(gf[mt],     bh0, aR[mt], 0, 0, 0);
                    aR[mt] = __builtin_amdgcn_mfma_f32_16x16x32_bf16(gf[4 + mt], bh1, aR[mt], 0, 0, 0);
                }
            }
            {
                short8 gf[8];
#pragma unroll
                for (int mt = 0; mt < 4; ++mt) {
                    gf[mt]     = *(const short8*)(whh + ((4 + mt) * 16 + arow) * 64 + grp * 8);
                    gf[4 + mt] = *(const short8*)(whh + ((4 + mt) * 16 + arow) * 64 + 32 + grp * 8);
                }
#pragma unroll
                for (int mt = 0; mt < 4; ++mt) {
                    aZ[mt] = __builtin_amdgcn_mfma_f32_16x16x32_bf16(gf[mt],     bh0, aZ[mt], 0, 0, 0);
                    aZ[mt] = __builtin_amdgcn_mfma_f32_16x16x32_bf16(gf[4 + mt], bh1, aZ[mt], 0, 0, 0);
                }
            }
            {
                short8 gf[8];
#pragma unroll
                for (int mt = 0; mt < 4; ++mt) {
                    gf[mt]     = *(const short8*)(whh + ((8 + mt) * 16 + arow) * 64 + grp * 8);
                    gf[4 + mt] = *(const short8*)(whh + ((8 + mt) * 16 + arow) * 64 + 32 + grp * 8);
                }
#pragma unroll
                for (int mt = 0; mt < 4; ++mt) {
                    aHN[mt] = __builtin_amdgcn_mfma_f32_16x16x32_bf16(gf[mt],     bh0, aHN[mt], 0, 0, 0);
                    aHN[mt] = __builtin_amdgcn_mfma_f32_16x16x32_bf16(gf[4 + mt], bh1, aHN[mt], 0, 0, 0);
                }
            }
        }
        // ---- GRU cell; h (t0) + relu(h) to LDS; t1 reads h back (bf16) ----
#pragma unroll
        for (int mt = 0; mt < 4; ++mt) {
            f32x4 hold;
            if (t == 0) {
                hold = (f32x4){0.f, 0.f, 0.f, 0.f};
            } else {
                uint2 hv = *(const uint2*)(Hw + bcol * 144 + mt * 32 + grp * 8);
                hold[0] = __uint_as_float(hv.x << 16);
                hold[1] = __uint_as_float(hv.x & 0xffff0000u);
                hold[2] = __uint_as_float(hv.y << 16);
                hold[3] = __uint_as_float(hv.y & 0xffff0000u);
            }
            f32x4 h2;
#pragma unroll
            for (int r = 0; r < 4; ++r) {
                float rg = sigf(aR[mt][r]);
                float zg = sigf(aZ[mt][r]);
                float nn = tanhfast(aXN[mt][r] + rg * aHN[mt][r]);
                h2[r] = nn + zg * (hold[r] - nn);
            }
            unsigned short a0 = f2bf(fmaxf(h2[0], 0.f)), a1 = f2bf(fmaxf(h2[1], 0.f));
            unsigned short a2 = f2bf(fmaxf(h2[2], 0.f)), a3 = f2bf(fmaxf(h2[3], 0.f));
            uint2 pa; pa.x = (unsigned)a0 | ((unsigned)a1 << 16); pa.y = (unsigned)a2 | ((unsigned)a3 << 16);
            if (t == 0) {
                unsigned short s0 = f2bf(h2[0]), s1 = f2bf(h2[1]), s2 = f2bf(h2[2]), s3 = f2bf(h2[3]);
                uint2 ph; ph.x = (unsigned)s0 | ((unsigned)s1 << 16); ph.y = (unsigned)s2 | ((unsigned)s3 << 16);
                *(uint2*)(Hw + bcol * 144 + mt * 32 + grp * 8) = ph;
            }
            *(uint2*)(Aw + bcol * 144 + mt * 32 + grp * 8) = pa;
        }
        // ---- MLP layer 1 ----
        {
            const unsigned short* w1p = zb + 18432;
            short8 wf[8];
#pragma unroll
            for (int mt = 0; mt < 4; ++mt) {
                wf[mt]     = *(const short8*)(w1p + (mt * 16 + arow) * 64 + grp * 8);
                wf[4 + mt] = *(const short8*)(w1p + (mt * 16 + arow) * 64 + 32 + grp * 8);
            }
            short8 ba0 = *(const short8*)(Aw + bcol * 144 + grp * 16);
            short8 ba1 = *(const short8*)(Aw + bcol * 144 + 64 + grp * 16);
            f32x4 m1[4];
#pragma unroll
            for (int mt = 0; mt < 4; ++mt) {
                m1[mt] = *(const f32x4*)&b1[n * 64 + mt * 16 + ch0];
                m1[mt] = __builtin_amdgcn_mfma_f32_16x16x32_bf16(wf[mt],     ba0, m1[mt], 0, 0, 0);
                m1[mt] = __builtin_amdgcn_mfma_f32_16x16x32_bf16(wf[4 + mt], ba1, m1[mt], 0, 0, 0);
            }
#pragma unroll
            for (int mt = 0; mt < 4; ++mt) {
                unsigned short m0 = f2bf(fmaxf(m1[mt][0], 0.f)), m1s = f2bf(fmaxf(m1[mt][1], 0.f));
                unsigned short m2 = f2bf(fmaxf(m1[mt][2], 0.f)), m3 = f2bf(fmaxf(m1[mt][3], 0.f));
                uint2 pm; pm.x = (unsigned)m0 | ((unsigned)m1s << 16); pm.y = (unsigned)m2 | ((unsigned)m3 << 16);
                *(uint2*)(Aw + bcol * 144 + mt * 32 + grp * 8) = pm;
            }
        }
        // ---- MLP layer 2 + head ----
        {
            const unsigned short* w2p = zb + 22528;
            short8 wf[8];
#pragma unroll
            for (int mt = 0; mt < 4; ++mt) {
                wf[mt]     = *(const short8*)(w2p + (mt * 16 + arow) * 64 + grp * 8);
                wf[4 + mt] = *(const short8*)(w2p + (mt * 16 + arow) * 64 + 32 + grp * 8);
            }
            short8 bm0 = *(const short8*)(Aw + bcol * 144 + grp * 16);
            short8 bm1 = *(const short8*)(Aw + bcol * 144 + 64 + grp * 16);
            float part = 0.f;
#pragma unroll
            for (int mt = 0; mt < 4; ++mt) {
                f32x4 m2 = *(const f32x4*)&b2[n * 64 + mt * 16 + ch0];
                m2 = __builtin_amdgcn_mfma_f32_16x16x32_bf16(wf[mt],     bm0, m2, 0, 0, 0);
                m2 = __builtin_amdgcn_mfma_f32_16x16x32_bf16(wf[4 + mt], bm1, m2, 0, 0, 0);
                f32x4 w3v = *(const f32x4*)&W3[n * 64 + mt * 16 + ch0];
#pragma unroll
                for (int r = 0; r < 4; ++r)
                    part += w3v[r] * fmaxf(m2[r], 0.f);
            }
            part += __shfl_xor(part, 16, 64);
            part += __shfl_xor(part, 32, 64);
            float val = 3.f * (sigf(part + b3v) - 0.5f);
            if (l < 16)
                p_flat[n * 4096 + (b0 + w * 16 + bcol) * 2 + t] = val;   // (n,b,t)-major
        }
    }
}

// ---------------------------------------------------------------------------
// Critic + p-last gather: grid 2048, block 64 (one wave per batch row).
// Only zone 99 contributes; neighbors {99,89,0,0,98}.
// ---------------------------------------------------------------------------
__global__ __launch_bounds__(64, 4)
void critic_kernel(const float* __restrict__ x, const float* __restrict__ p_flat,
                   const float* __restrict__ lmW1, const float* __restrict__ lmb1,
                   const float* __restrict__ lmW2, const float* __restrict__ lmb2,
                   const float* __restrict__ lmW3, const float* __restrict__ lmb3,
                   const float* __restrict__ scWih, const float* __restrict__ scWhh,
                   const float* __restrict__ scbih, const float* __restrict__ scbhh,
                   const float* __restrict__ scW1, const float* __restrict__ scb1,
                   const float* __restrict__ scW2, const float* __restrict__ scb2,
                   const float* __restrict__ scW3, const float* __restrict__ scb3,
                   float* __restrict__ out)
{
    __shared__ float sxi[72];
    __shared__ float shh[68];
    __shared__ float sab[68];
    __shared__ float sc1[68];
    __shared__ float sf1[132];

    const int lane = threadIdx.x;
    const int b = blockIdx.x;

    for (int idx = lane; idx < 72; idx += 64) {
        int t = idx / 36, c = idx - t * 36;
        float v = 0.f;
        if (c < 35) {
            int g = c / 7, e = c - g * 7;
            int z = (g == 0) ? 99 : (g == 1) ? 89 : (g == 4) ? 98 : -1;
            if (z >= 0)
                v = (e < 6) ? x[((size_t)b * 2 + t) * 600 + z * 6 + e]
                            : p_flat[b * 200 + t * 100 + z];
        }
        sxi[idx] = v;
    }
    __syncthreads();

    float cg00 = scbih[lane], cg01 = scbih[lane + 64], cg02 = scbih[lane + 128];
    float cg10 = cg00, cg11 = cg01, cg12 = cg02;
    for (int c = 0; c < 35; ++c) {
        float w0 = scWih[lane * 35 + c];
        float w1 = scWih[(lane + 64) * 35 + c];
        float w2 = scWih[(lane + 128) * 35 + c];
        float x0 = sxi[c], x1 = sxi[36 + c];
        cg00 += w0 * x0; cg01 += w1 * x0; cg02 += w2 * x0;
        cg10 += w0 * x1; cg11 += w1 * x1; cg12 += w2 * x1;
    }
    const float bhr = scbhh[lane], bhz = scbhh[lane + 64], bhn = scbhh[lane + 128];
    float r  = 1.f / (1.f + expf(-(cg00 + bhr)));
    float zg = 1.f / (1.f + expf(-(cg01 + bhz)));
    float nn = tanhf(cg02 + r * bhn);
    float hj = (1.f - zg) * nn;
    shh[lane] = hj;
    __syncthreads();
    float ghr = bhr, ghz = bhz, ghn = bhn;
    for (int kc = 0; kc < 16; ++kc) {
        float4 wr  = *(const float4*)&scWhh[lane * 64 + kc * 4];
        float4 wzv = *(const float4*)&scWhh[(lane + 64) * 64 + kc * 4];
        float4 wn  = *(const float4*)&scWhh[(lane + 128) * 64 + kc * 4];
        float4 hv  = *(const float4*)&shh[kc * 4];
        ghr += wr.x * hv.x + wr.y * hv.y + wr.z * hv.z + wr.w * hv.w;
        ghz += wzv.x * hv.x + wzv.y * hv.y + wzv.z * hv.z + wzv.w * hv.w;
        ghn += wn.x * hv.x + wn.y * hv.y + wn.z * hv.z + wn.w * hv.w;
    }
    r  = 1.f / (1.f + expf(-(cg10 + ghr)));
    zg = 1.f / (1.f + expf(-(cg11 + ghz)));
    nn = tanhf(cg12 + r * ghn);
    hj = (1.f - zg) * nn + zg * hj;
    sab[lane] = fmaxf(hj, 0.f);
    __syncthreads();
    float acc = scb1[lane];
    for (int kc = 0; kc < 16; ++kc) {
        float4 wv = *(const float4*)&scW1[lane * 64 + kc * 4];
        float4 av = *(const float4*)&sab[kc * 4];
        acc += wv.x * av.x + wv.y * av.y + wv.z * av.z + wv.w * av.w;
    }
    sc1[lane] = fmaxf(acc, 0.f);
    __syncthreads();
    float acc2 = scb2[lane];
    for (int kc = 0; kc < 16; ++kc) {
        float4 wv = *(const float4*)&scW2[lane * 64 + kc * 4];
        float4 av = *(const float4*)&sc1[kc * 4];
        acc2 += wv.x * av.x + wv.y * av.y + wv.z * av.z + wv.w * av.w;
    }
    float qpart = scW3[lane] * fmaxf(acc2, 0.f);
    float f1a = lmb1[lane], f1c = lmb1[lane + 64];
    for (int c = 0; c < 35; ++c) {
        float xv = sxi[36 + c];
        f1a += lmW1[lane * 35 + c] * xv;
        f1c += lmW1[(lane + 64) * 35 + c] * xv;
    }
    sf1[lane] = fmaxf(f1a, 0.f);
    sf1[lane + 64] = fmaxf(f1c, 0.f);
    __syncthreads();
    float f2a = lmb2[lane], f2c = lmb2[lane + 64];
    for (int kc = 0; kc < 32; ++kc) {
        float4 fv = *(const float4*)&sf1[kc * 4];
        float4 wa = *(const float4*)&lmW2[lane * 128 + kc * 4];
        float4 wc = *(const float4*)&lmW2[(lane + 64) * 128 + kc * 4];
        f2a += wa.x * fv.x + wa.y * fv.y + wa.z * fv.z + wa.w * fv.w;
        f2c += wc.x * fv.x + wc.y * fv.y + wc.z * fv.z + wc.w * fv.w;
    }
    float fpart = lmW3[lane] * fmaxf(f2a, 0.f) + lmW3[lane + 64] * fmaxf(f2c, 0.f);

    float tot = qpart + fpart;
    for (int m = 32; m > 0; m >>= 1) tot += __shfl_xor(tot, m, 64);
    if (lane == 0) out[204800 + b] = tot + scb3[0] + lmb3[0];

    for (int l2 = lane; l2 < 100; l2 += 64)
        out[b * 100 + l2] = p_flat[b * 200 + 100 + l2];
}

extern "C" void kernel_launch(void* const* d_in, const int* in_sizes, int n_in,
                              void* d_out, int out_size, void* d_ws, size_t ws_size,
                              hipStream_t stream) {
    const float* x     = (const float*)d_in[0];
    const float* aWih  = (const float*)d_in[1];
    const float* aWhh  = (const float*)d_in[2];
    const float* abih  = (const float*)d_in[3];
    const float* abhh  = (const float*)d_in[4];
    const float* aW1   = (const float*)d_in[5];
    const float* ab1   = (const float*)d_in[6];
    const float* aW2   = (const float*)d_in[7];
    const float* ab2   = (const float*)d_in[8];
    const float* aW3   = (const float*)d_in[9];
    const float* ab3   = (const float*)d_in[10];
    const float* lmW1  = (const float*)d_in[11];
    const float* lmb1  = (const float*)d_in[12];
    const float* lmW2  = (const float*)d_in[13];
    const float* lmb2  = (const float*)d_in[14];
    const float* lmW3  = (const float*)d_in[15];
    const float* lmb3  = (const float*)d_in[16];
    const float* scWih = (const float*)d_in[17];
    const float* scWhh = (const float*)d_in[18];
    const float* scbih = (const float*)d_in[19];
    const float* scbhh = (const float*)d_in[20];
    const float* scW1  = (const float*)d_in[21];
    const float* scb1  = (const float*)d_in[22];
    const float* scW2  = (const float*)d_in[23];
    const float* scb2  = (const float*)d_in[24];
    const float* scW3  = (const float*)d_in[25];
    const float* scb3  = (const float*)d_in[26];
    float* out = (float*)d_out;
    float* p_flat = (float*)d_ws;                                          // 1.6 MB
    unsigned short* wz = (unsigned short*)((char*)d_ws + WS_W_OFF_BYTES);  // 5.3 MB

    convert_kernel<<<dim3((100 * ZW + 255) / 256), 256, 0, stream>>>(
        aWih, aWhh, aW1, aW2, wz);

    actor_kernel<<<dim3(32, 100), 256, 0, stream>>>(
        x, wz, abih, abhh, ab1, ab2, aW3, ab3, p_flat);

    critic_kernel<<<dim3(2048), 64, 0, stream>>>(
        x, p_flat, lmW1, lmb1, lmW2, lmb2, lmW3, lmb3,
        scWih, scWhh, scbih, scbhh, scW1, scb1, scW2, scb2, scW3, scb3, out);
}

// Round 5
// 200.981 us; speedup vs baseline: 1.0264x; 1.0264x over previous
//
#include <hip/hip_runtime.h>
#include <hip/hip_bf16.h>

typedef __attribute__((ext_vector_type(8))) short short8;
typedef __attribute__((ext_vector_type(4))) float f32x4;

// ---- ws layout: p_flat (409600 f32 = 1638400 B) then bf16 weight slabs ----
// per zone (shorts): Wih [192][32] @0, Whh [192][64] @6144,
//                    W1 [64][64] @18432, W2 [64][64] @22528; stride 26624.
#define ZW 26624
#define WS_W_OFF_BYTES 1638400

__device__ __forceinline__ unsigned short f2bf(float f) {
    unsigned u = __float_as_uint(f);
    return (unsigned short)((u + 0x7FFFu + ((u >> 16) & 1u)) >> 16);  // RNE
}
__device__ __forceinline__ float sigf(float x) {
    return __builtin_amdgcn_rcpf(1.f + __builtin_amdgcn_exp2f(-1.4426950408889634f * x));
}
__device__ __forceinline__ float tanhfast(float y) {
    return 1.f - 2.f * __builtin_amdgcn_rcpf(1.f + __builtin_amdgcn_exp2f(2.8853900817779268f * y));
}

// ---------------------------------------------------------------------------
// Pre-pass: convert actor weights f32 -> bf16 fragment-ready slabs in ws.
// ---------------------------------------------------------------------------
__global__ __launch_bounds__(256)
void convert_kernel(const float* __restrict__ Wih, const float* __restrict__ Whh,
                    const float* __restrict__ W1, const float* __restrict__ W2,
                    unsigned short* __restrict__ dst)
{
    int idx = blockIdx.x * 256 + threadIdx.x;
    if (idx >= 100 * ZW) return;
    int n = idx / ZW;
    int i = idx - n * ZW;
    float v;
    if (i < 6144) {
        int row = i >> 5, k = i & 31;
        v = (k < 6) ? Wih[n * 1152 + row * 6 + k] : 0.f;
    } else if (i < 18432) {
        v = Whh[n * 12288 + (i - 6144)];
    } else if (i < 22528) {
        v = W1[n * 4096 + (i - 18432)];
    } else {
        v = W2[n * 4096 + (i - 22528)];
    }
    dst[idx] = f2bf(v);
}

// ---------------------------------------------------------------------------
// Actor (MFMA bf16, lean registers): grid (32,100), block 256 = 4 independent
// waves. Wave w owns batches b0+w*16..+15. lane: bcol/arow = l&15, grp = l>>4.
// GRU gates processed PER M-TILE so only 16 accumulator regs are live at once
// (target: <=64 unified VGPR+AGPR -> 8 waves/SIMD). No __syncthreads.
// C/D: col=lane&15 (batch), row=(lane>>4)*4+reg (channel)  [m89-verified].
// LDS = 20480 B exactly -> 8 blocks/CU.
// ---------------------------------------------------------------------------
__global__ __launch_bounds__(256, 8)
void actor_kernel(const float* __restrict__ x, const unsigned short* __restrict__ wz,
                  const float* __restrict__ bih, const float* __restrict__ bhh,
                  const float* __restrict__ b1, const float* __restrict__ b2,
                  const float* __restrict__ W3, const float* __restrict__ b3,
                  float* __restrict__ p_flat)
{
    __shared__ char sm[20480];
    const int tid = threadIdx.x;
    const int n   = blockIdx.y;
    const int b0  = blockIdx.x * 64;
    const int w    = tid >> 6;
    const int l    = tid & 63;
    const int bcol = l & 15;
    const int grp  = l >> 4;
    const int arow = bcol;
    const int ch0  = grp * 4;
    const unsigned short* zb = wz + (size_t)n * ZW;
    char* uXw = sm + w * 512;              // [2 t][16 b][8 k] shorts
    char* Hw  = sm + 2048 + w * 2304;      // [16 b][72] shorts (h, bf16)
    char* Aw  = sm + 11264 + w * 2304;     // [16 b][72] shorts (act / m1)

    // ---- wave-local x staging (bf16, K=8 zero-padded) ----
    for (int i = l; i < 256; i += 64) {
        int k = i & 7, b = (i >> 3) & 15, t = i >> 7;
        ((unsigned short*)uXw)[i] = (k < 6)
            ? f2bf(x[(size_t)(b0 + w * 16 + b) * 1200 + t * 600 + n * 6 + k])
            : (unsigned short)0;
    }

    const float* bihz = bih + n * 192;
    const float* bhhz = bhh + n * 192;
    const float b3v = b3[n];

    for (int t = 0; t < 2; ++t) {
        short8 bx = *(const short8*)(uXw + t * 256 + bcol * 16);
        short8 bh0, bh1;
        if (t == 1) {
            bh0 = *(const short8*)(Hw + bcol * 144 + grp * 16);
            bh1 = *(const short8*)(Hw + bcol * 144 + 64 + grp * 16);
        }
        const unsigned short* whh = zb + 6144;
        // ---- GRU gates + cell, one M-tile at a time (16 accs live) ----
#pragma unroll
        for (int mt = 0; mt < 4; ++mt) {
            const int ch = mt * 16 + ch0;
            f32x4 aR  = *(const f32x4*)&bihz[ch]       + *(const f32x4*)&bhhz[ch];
            f32x4 aZ  = *(const f32x4*)&bihz[64 + ch]  + *(const f32x4*)&bhhz[64 + ch];
            f32x4 aXN = *(const f32x4*)&bihz[128 + ch];
            f32x4 aHN = *(const f32x4*)&bhhz[128 + ch];
            aR  = __builtin_amdgcn_mfma_f32_16x16x32_bf16(
                      *(const short8*)(zb + ((0 + mt) * 16 + arow) * 32 + grp * 8), bx, aR, 0, 0, 0);
            aZ  = __builtin_amdgcn_mfma_f32_16x16x32_bf16(
                      *(const short8*)(zb + ((4 + mt) * 16 + arow) * 32 + grp * 8), bx, aZ, 0, 0, 0);
            aXN = __builtin_amdgcn_mfma_f32_16x16x32_bf16(
                      *(const short8*)(zb + ((8 + mt) * 16 + arow) * 32 + grp * 8), bx, aXN, 0, 0, 0);
            if (t == 1) {
                aR  = __builtin_amdgcn_mfma_f32_16x16x32_bf16(
                          *(const short8*)(whh + ((0 + mt) * 16 + arow) * 64 + grp * 8), bh0, aR, 0, 0, 0);
                aR  = __builtin_amdgcn_mfma_f32_16x16x32_bf16(
                          *(const short8*)(whh + ((0 + mt) * 16 + arow) * 64 + 32 + grp * 8), bh1, aR, 0, 0, 0);
                aZ  = __builtin_amdgcn_mfma_f32_16x16x32_bf16(
                          *(const short8*)(whh + ((4 + mt) * 16 + arow) * 64 + grp * 8), bh0, aZ, 0, 0, 0);
                aZ  = __builtin_amdgcn_mfma_f32_16x16x32_bf16(
                          *(const short8*)(whh + ((4 + mt) * 16 + arow) * 64 + 32 + grp * 8), bh1, aZ, 0, 0, 0);
                aHN = __builtin_amdgcn_mfma_f32_16x16x32_bf16(
                          *(const short8*)(whh + ((8 + mt) * 16 + arow) * 64 + grp * 8), bh0, aHN, 0, 0, 0);
                aHN = __builtin_amdgcn_mfma_f32_16x16x32_bf16(
                          *(const short8*)(whh + ((8 + mt) * 16 + arow) * 64 + 32 + grp * 8), bh1, aHN, 0, 0, 0);
            }
            // cell
            f32x4 hold;
            if (t == 0) {
                hold = (f32x4){0.f, 0.f, 0.f, 0.f};
            } else {
                uint2 hv = *(const uint2*)(Hw + bcol * 144 + mt * 32 + grp * 8);
                hold[0] = __uint_as_float(hv.x << 16);
                hold[1] = __uint_as_float(hv.x & 0xffff0000u);
                hold[2] = __uint_as_float(hv.y << 16);
                hold[3] = __uint_as_float(hv.y & 0xffff0000u);
            }
            f32x4 h2;
#pragma unroll
            for (int r = 0; r < 4; ++r) {
                float rg = sigf(aR[r]);
                float zg = sigf(aZ[r]);
                float nn = tanhfast(aXN[r] + rg * aHN[r]);
                h2[r] = nn + zg * (hold[r] - nn);
            }
            unsigned short a0 = f2bf(fmaxf(h2[0], 0.f)), a1 = f2bf(fmaxf(h2[1], 0.f));
            unsigned short a2 = f2bf(fmaxf(h2[2], 0.f)), a3 = f2bf(fmaxf(h2[3], 0.f));
            uint2 pa; pa.x = (unsigned)a0 | ((unsigned)a1 << 16); pa.y = (unsigned)a2 | ((unsigned)a3 << 16);
            if (t == 0) {
                unsigned short s0 = f2bf(h2[0]), s1 = f2bf(h2[1]), s2 = f2bf(h2[2]), s3 = f2bf(h2[3]);
                uint2 ph; ph.x = (unsigned)s0 | ((unsigned)s1 << 16); ph.y = (unsigned)s2 | ((unsigned)s3 << 16);
                *(uint2*)(Hw + bcol * 144 + mt * 32 + grp * 8) = ph;
            }
            *(uint2*)(Aw + bcol * 144 + mt * 32 + grp * 8) = pa;
        }
        // ---- MLP layer 1 (per M-tile; 4 accs live) ----
        {
            const unsigned short* w1p = zb + 18432;
            short8 ba0 = *(const short8*)(Aw + bcol * 144 + grp * 16);
            short8 ba1 = *(const short8*)(Aw + bcol * 144 + 64 + grp * 16);
            f32x4 m1o[4];
#pragma unroll
            for (int mt = 0; mt < 4; ++mt) {
                f32x4 m1 = *(const f32x4*)&b1[n * 64 + mt * 16 + ch0];
                m1 = __builtin_amdgcn_mfma_f32_16x16x32_bf16(
                         *(const short8*)(w1p + (mt * 16 + arow) * 64 + grp * 8), ba0, m1, 0, 0, 0);
                m1 = __builtin_amdgcn_mfma_f32_16x16x32_bf16(
                         *(const short8*)(w1p + (mt * 16 + arow) * 64 + 32 + grp * 8), ba1, m1, 0, 0, 0);
                m1o[mt] = m1;
            }
#pragma unroll
            for (int mt = 0; mt < 4; ++mt) {
                unsigned short m0 = f2bf(fmaxf(m1o[mt][0], 0.f)), m1s = f2bf(fmaxf(m1o[mt][1], 0.f));
                unsigned short m2 = f2bf(fmaxf(m1o[mt][2], 0.f)), m3 = f2bf(fmaxf(m1o[mt][3], 0.f));
                uint2 pm; pm.x = (unsigned)m0 | ((unsigned)m1s << 16); pm.y = (unsigned)m2 | ((unsigned)m3 << 16);
                *(uint2*)(Aw + bcol * 144 + mt * 32 + grp * 8) = pm;
            }
        }
        // ---- MLP layer 2 + head (per M-tile; 4 accs live) ----
        {
            const unsigned short* w2p = zb + 22528;
            short8 bm0 = *(const short8*)(Aw + bcol * 144 + grp * 16);
            short8 bm1 = *(const short8*)(Aw + bcol * 144 + 64 + grp * 16);
            float part = 0.f;
#pragma unroll
            for (int mt = 0; mt < 4; ++mt) {
                f32x4 m2 = *(const f32x4*)&b2[n * 64 + mt * 16 + ch0];
                m2 = __builtin_amdgcn_mfma_f32_16x16x32_bf16(
                         *(const short8*)(w2p + (mt * 16 + arow) * 64 + grp * 8), bm0, m2, 0, 0, 0);
                m2 = __builtin_amdgcn_mfma_f32_16x16x32_bf16(
                         *(const short8*)(w2p + (mt * 16 + arow) * 64 + 32 + grp * 8), bm1, m2, 0, 0, 0);
                f32x4 w3v = *(const f32x4*)&W3[n * 64 + mt * 16 + ch0];
#pragma unroll
                for (int r = 0; r < 4; ++r)
                    part += w3v[r] * fmaxf(m2[r], 0.f);
            }
            part += __shfl_xor(part, 16, 64);
            part += __shfl_xor(part, 32, 64);
            float val = 3.f * (sigf(part + b3v) - 0.5f);
            if (l < 16)
                p_flat[n * 4096 + (b0 + w * 16 + bcol) * 2 + t] = val;   // (n,b,t)-major
        }
    }
}

// ---------------------------------------------------------------------------
// Critic + p-last gather (round-3 form): grid 512, block 256, wave/batch row.
// Only zone 99 contributes; neighbors {99,89,0,0,98}.
// ---------------------------------------------------------------------------
__global__ __launch_bounds__(256, 2)
void critic_kernel(const float* __restrict__ x, const float* __restrict__ p_flat,
                   const float* __restrict__ lmW1, const float* __restrict__ lmb1,
                   const float* __restrict__ lmW2, const float* __restrict__ lmb2,
                   const float* __restrict__ lmW3, const float* __restrict__ lmb3,
                   const float* __restrict__ scWih, const float* __restrict__ scWhh,
                   const float* __restrict__ scbih, const float* __restrict__ scbhh,
                   const float* __restrict__ scW1, const float* __restrict__ scb1,
                   const float* __restrict__ scW2, const float* __restrict__ scb2,
                   const float* __restrict__ scW3, const float* __restrict__ scb3,
                   float* __restrict__ out)
{
    __shared__ float sxi[4][72];
    __shared__ float shh[4][68];
    __shared__ float sab[4][68];
    __shared__ float sc1[4][68];
    __shared__ float sf1[4][132];

    const int tid = threadIdx.x;
    const int wid = tid >> 6;
    const int lane = tid & 63;
    const int b = blockIdx.x * 4 + wid;

    for (int idx = lane; idx < 72; idx += 64) {
        int t = idx / 36, c = idx - t * 36;
        float v = 0.f;
        if (c < 35) {
            int g = c / 7, e = c - g * 7;
            int z = (g == 0) ? 99 : (g == 1) ? 89 : (g == 4) ? 98 : -1;
            if (z >= 0)
                v = (e < 6) ? x[((size_t)b * 2 + t) * 600 + z * 6 + e]
                            : p_flat[b * 200 + t * 100 + z];
        }
        sxi[wid][idx] = v;
    }
    __syncthreads();

    float cg00 = scbih[lane], cg01 = scbih[lane + 64], cg02 = scbih[lane + 128];
    float cg10 = cg00, cg11 = cg01, cg12 = cg02;
    for (int c = 0; c < 35; ++c) {
        float w0 = scWih[lane * 35 + c];
        float w1 = scWih[(lane + 64) * 35 + c];
        float w2 = scWih[(lane + 128) * 35 + c];
        float x0 = sxi[wid][c], x1 = sxi[wid][36 + c];
        cg00 += w0 * x0; cg01 += w1 * x0; cg02 += w2 * x0;
        cg10 += w0 * x1; cg11 += w1 * x1; cg12 += w2 * x1;
    }
    const float bhr = scbhh[lane], bhz = scbhh[lane + 64], bhn = scbhh[lane + 128];
    float r  = 1.f / (1.f + expf(-(cg00 + bhr)));
    float zg = 1.f / (1.f + expf(-(cg01 + bhz)));
    float nn = tanhf(cg02 + r * bhn);
    float hj = (1.f - zg) * nn;
    shh[wid][lane] = hj;
    __syncthreads();
    float ghr = bhr, ghz = bhz, ghn = bhn;
    for (int kc = 0; kc < 16; ++kc) {
        float4 wr  = *(const float4*)&scWhh[lane * 64 + kc * 4];
        float4 wzv = *(const float4*)&scWhh[(lane + 64) * 64 + kc * 4];
        float4 wn  = *(const float4*)&scWhh[(lane + 128) * 64 + kc * 4];
        float4 hv  = *(const float4*)&shh[wid][kc * 4];
        ghr += wr.x * hv.x + wr.y * hv.y + wr.z * hv.z + wr.w * hv.w;
        ghz += wzv.x * hv.x + wzv.y * hv.y + wzv.z * hv.z + wzv.w * hv.w;
        ghn += wn.x * hv.x + wn.y * hv.y + wn.z * hv.z + wn.w * hv.w;
    }
    r  = 1.f / (1.f + expf(-(cg10 + ghr)));
    zg = 1.f / (1.f + expf(-(cg11 + ghz)));
    nn = tanhf(cg12 + r * ghn);
    hj = (1.f - zg) * nn + zg * hj;
    sab[wid][lane] = fmaxf(hj, 0.f);
    __syncthreads();
    float acc = scb1[lane];
    for (int kc = 0; kc < 16; ++kc) {
        float4 wv = *(const float4*)&scW1[lane * 64 + kc * 4];
        float4 av = *(const float4*)&sab[wid][kc * 4];
        acc += wv.x * av.x + wv.y * av.y + wv.z * av.z + wv.w * av.w;
    }
    sc1[wid][lane] = fmaxf(acc, 0.f);
    __syncthreads();
    float acc2 = scb2[lane];
    for (int kc = 0; kc < 16; ++kc) {
        float4 wv = *(const float4*)&scW2[lane * 64 + kc * 4];
        float4 av = *(const float4*)&sc1[wid][kc * 4];
        acc2 += wv.x * av.x + wv.y * av.y + wv.z * av.z + wv.w * av.w;
    }
    float qpart = scW3[lane] * fmaxf(acc2, 0.f);
    float f1a = lmb1[lane], f1c = lmb1[lane + 64];
    for (int c = 0; c < 35; ++c) {
        float xv = sxi[wid][36 + c];
        f1a += lmW1[lane * 35 + c] * xv;
        f1c += lmW1[(lane + 64) * 35 + c] * xv;
    }
    sf1[wid][lane] = fmaxf(f1a, 0.f);
    sf1[wid][lane + 64] = fmaxf(f1c, 0.f);
    __syncthreads();
    float f2a = lmb2[lane], f2c = lmb2[lane + 64];
    for (int kc = 0; kc < 32; ++kc) {
        float4 fv = *(const float4*)&sf1[wid][kc * 4];
        float4 wa = *(const float4*)&lmW2[lane * 128 + kc * 4];
        float4 wc = *(const float4*)&lmW2[(lane + 64) * 128 + kc * 4];
        f2a += wa.x * fv.x + wa.y * fv.y + wa.z * fv.z + wa.w * fv.w;
        f2c += wc.x * fv.x + wc.y * fv.y + wc.z * fv.z + wc.w * fv.w;
    }
    float fpart = lmW3[lane] * fmaxf(f2a, 0.f) + lmW3[lane + 64] * fmaxf(f2c, 0.f);

    float tot = qpart + fpart;
    for (int m = 32; m > 0; m >>= 1) tot += __shfl_xor(tot, m, 64);
    if (lane == 0) out[204800 + b] = tot + scb3[0] + lmb3[0];

    for (int l2 = lane; l2 < 100; l2 += 64)
        out[b * 100 + l2] = p_flat[b * 200 + 100 + l2];
}

extern "C" void kernel_launch(void* const* d_in, const int* in_sizes, int n_in,
                              void* d_out, int out_size, void* d_ws, size_t ws_size,
                              hipStream_t stream) {
    const float* x     = (const float*)d_in[0];
    const float* aWih  = (const float*)d_in[1];
    const float* aWhh  = (const float*)d_in[2];
    const float* abih  = (const float*)d_in[3];
    const float* abhh  = (const float*)d_in[4];
    const float* aW1   = (const float*)d_in[5];
    const float* ab1   = (const float*)d_in[6];
    const float* aW2   = (const float*)d_in[7];
    const float* ab2   = (const float*)d_in[8];
    const float* aW3   = (const float*)d_in[9];
    const float* ab3   = (const float*)d_in[10];
    const float* lmW1  = (const float*)d_in[11];
    const float* lmb1  = (const float*)d_in[12];
    const float* lmW2  = (const float*)d_in[13];
    const float* lmb2  = (const float*)d_in[14];
    const float* lmW3  = (const float*)d_in[15];
    const float* lmb3  = (const float*)d_in[16];
    const float* scWih = (const float*)d_in[17];
    const float* scWhh = (const float*)d_in[18];
    const float* scbih = (const float*)d_in[19];
    const float* scbhh = (const float*)d_in[20];
    const float* scW1  = (const float*)d_in[21];
    const float* scb1  = (const float*)d_in[22];
    const float* scW2  = (const float*)d_in[23];
    const float* scb2  = (const float*)d_in[24];
    const float* scW3  = (const float*)d_in[25];
    const float* scb3  = (const float*)d_in[26];
    float* out = (float*)d_out;
    float* p_flat = (float*)d_ws;                                          // 1.6 MB
    unsigned short* wz = (unsigned short*)((char*)d_ws + WS_W_OFF_BYTES);  // 5.3 MB

    convert_kernel<<<dim3((100 * ZW + 255) / 256), 256, 0, stream>>>(
        aWih, aWhh, aW1, aW2, wz);

    actor_kernel<<<dim3(32, 100), 256, 0, stream>>>(
        x, wz, abih, abhh, ab1, ab2, aW3, ab3, p_flat);

    critic_kernel<<<dim3(512), 256, 0, stream>>>(
        x, p_flat, lmW1, lmb1, lmW2, lmb2, lmW3, lmb3,
        scWih, scWhh, scbih, scbhh, scW1, scb1, scW2, scb2, scW3, scb3, out);
}

// Round 6
// 198.349 us; speedup vs baseline: 1.0400x; 1.0133x over previous
//
#include <hip/hip_runtime.h>
#include <hip/hip_bf16.h>

typedef __attribute__((ext_vector_type(8))) short short8;
typedef __attribute__((ext_vector_type(4))) float f32x4;

// ---- ws layout: p_flat (409600 f32 = 1638400 B) then bf16 weight slabs ----
// per zone (shorts): Wih' [192][8] @0 (only real K-cols; cols 8..31 of the
// K=32 GEMM are zero and handled by zero-frags), Whh [192][64] @1536,
// W1 [64][64] @13824, W2 [64][64] @17920; stride ZW=22016 shorts (44 KB).
#define ZW 22016
#define WS_W_OFF_BYTES 1638400

__device__ __forceinline__ unsigned short f2bf(float f) {
    unsigned u = __float_as_uint(f);
    return (unsigned short)((u + 0x7FFFu + ((u >> 16) & 1u)) >> 16);  // RNE
}
__device__ __forceinline__ float sigf(float x) {
    return __builtin_amdgcn_rcpf(1.f + __builtin_amdgcn_exp2f(-1.4426950408889634f * x));
}
__device__ __forceinline__ float tanhfast(float y) {
    return 1.f - 2.f * __builtin_amdgcn_rcpf(1.f + __builtin_amdgcn_exp2f(2.8853900817779268f * y));
}

// ---------------------------------------------------------------------------
// Pre-pass: convert actor weights f32 -> bf16 fragment-ready slabs in ws.
// ---------------------------------------------------------------------------
__global__ __launch_bounds__(256)
void convert_kernel(const float* __restrict__ Wih, const float* __restrict__ Whh,
                    const float* __restrict__ W1, const float* __restrict__ W2,
                    unsigned short* __restrict__ dst)
{
    int idx = blockIdx.x * 256 + threadIdx.x;
    if (idx >= 100 * ZW) return;
    int n = idx / ZW;
    int i = idx - n * ZW;
    float v;
    if (i < 1536) {
        int row = i >> 3, k = i & 7;
        v = (k < 6) ? Wih[n * 1152 + row * 6 + k] : 0.f;
    } else if (i < 13824) {
        v = Whh[n * 12288 + (i - 1536)];
    } else if (i < 17920) {
        v = W1[n * 4096 + (i - 13824)];
    } else {
        v = W2[n * 4096 + (i - 17920)];
    }
    dst[idx] = f2bf(v);
}

// ---------------------------------------------------------------------------
// Actor: grid 1600 (linear), block 256 = 4 independent waves, 32 batches/wave
// (2 N-subtiles of 16). XCD-pinned work mapping: xcd = wgid&7 owns a fixed
// zone set, so each 44 KB slab lives in exactly one XCD's L2.
// Wave-private LDS tiles; NO __syncthreads anywhere.
// C/D: col=lane&15 (batch), row=(lane>>4)*4+reg (channel)  [m89-verified].
// Zero-frag trick: Wih'/x K-cols 8..31 are zero -> only grp==0 lanes load.
// ---------------------------------------------------------------------------
__global__ __launch_bounds__(256, 4)
void actor_kernel(const float* __restrict__ x, const unsigned short* __restrict__ wz,
                  const float* __restrict__ bih, const float* __restrict__ bhh,
                  const float* __restrict__ b1, const float* __restrict__ b2,
                  const float* __restrict__ W3, const float* __restrict__ b3,
                  float* __restrict__ p_flat)
{
    __shared__ char sm[40960];
    const int tid = threadIdx.x;
    // ---- XCD-pinned (zone, btile) mapping; bijection over 1600 blocks ----
    const int wid = blockIdx.x;
    const int xcd = wid & 7;
    const int s   = wid >> 3;            // 0..199
    int n, btile;
    if (s < 192) { n = xcd * 12 + (s >> 4); btile = s & 15; }
    else         { n = 96 + (xcd >> 1); btile = (xcd & 1) * 8 + (s - 192); }

    const int w    = tid >> 6;
    const int l    = tid & 63;
    const int bcol = l & 15;
    const int grp  = l >> 4;
    const int arow = bcol;
    const int ch0  = grp * 4;
    const int wb   = btile * 128 + w * 32;      // wave batch base
    const unsigned short* zb = wz + (size_t)n * ZW;

    char* uXw = sm + w * 1024;             // [2t][32b][8k] shorts
    char* Hw  = sm + 4096  + w * 4608;     // [32b][72ch] shorts (h)
    char* Aw  = sm + 22528 + w * 4608;     // [32b][72ch] shorts (act/m1)

    // ---- x staging: lane l handles row (t = l>>5, b = l&31); 6 reals + 2 pad
    {
        int t = l >> 5, b = l & 31;
        const float* xr = x + (size_t)(wb + b) * 1200 + t * 600 + n * 6;
        float2 v0 = *(const float2*)xr;
        float2 v1 = *(const float2*)(xr + 2);
        float2 v2 = *(const float2*)(xr + 4);
        uint4 pk;
        pk.x = (unsigned)f2bf(v0.x) | ((unsigned)f2bf(v0.y) << 16);
        pk.y = (unsigned)f2bf(v1.x) | ((unsigned)f2bf(v1.y) << 16);
        pk.z = (unsigned)f2bf(v2.x) | ((unsigned)f2bf(v2.y) << 16);
        pk.w = 0u;
        *(uint4*)(uXw + (t * 32 + b) * 16) = pk;
    }

    const float* bihz = bih + n * 192;
    const float* bhhz = bhh + n * 192;
    const float b3v = b3[n];
    const short8 zfrag = {0, 0, 0, 0, 0, 0, 0, 0};

    for (int t = 0; t < 2; ++t) {
        // ---- B-frags for gx (zero unless grp==0) ----
        short8 bx0 = zfrag, bx1 = zfrag;
        if (grp == 0) {
            bx0 = *(const short8*)(uXw + (t * 32 + bcol) * 16);
            bx1 = *(const short8*)(uXw + (t * 32 + 16 + bcol) * 16);
        }
        short8 bh00, bh01, bh10, bh11;
        if (t == 1) {
            bh00 = *(const short8*)(Hw + bcol * 144 + grp * 16);
            bh01 = *(const short8*)(Hw + bcol * 144 + 64 + grp * 16);
            bh10 = *(const short8*)(Hw + (16 + bcol) * 144 + grp * 16);
            bh11 = *(const short8*)(Hw + (16 + bcol) * 144 + 64 + grp * 16);
        }
        const unsigned short* whh = zb + 1536;
        // ---- GRU gates + cell, per M-tile (8 f32x4 accs live) ----
#pragma unroll
        for (int mt = 0; mt < 4; ++mt) {
            const int ch = mt * 16 + ch0;
            f32x4 bR  = *(const f32x4*)&bihz[ch]      + *(const f32x4*)&bhhz[ch];
            f32x4 bZ  = *(const f32x4*)&bihz[64 + ch] + *(const f32x4*)&bhhz[64 + ch];
            f32x4 aR0 = bR,  aR1 = bR;
            f32x4 aZ0 = bZ,  aZ1 = bZ;
            f32x4 aXN0 = *(const f32x4*)&bihz[128 + ch], aXN1 = aXN0;
            f32x4 aHN0 = *(const f32x4*)&bhhz[128 + ch], aHN1 = aHN0;
            // gx: 3 A-frags (grp0 only), each feeds 2 MFMAs
            short8 wr = zfrag, wzg = zfrag, wn = zfrag;
            if (grp == 0) {
                wr  = *(const short8*)(zb + (0 + mt) * 128 + arow * 8);
                wzg = *(const short8*)(zb + (4 + mt) * 128 + arow * 8);
                wn  = *(const short8*)(zb + (8 + mt) * 128 + arow * 8);
            }
            aR0  = __builtin_amdgcn_mfma_f32_16x16x32_bf16(wr,  bx0, aR0,  0, 0, 0);
            aR1  = __builtin_amdgcn_mfma_f32_16x16x32_bf16(wr,  bx1, aR1,  0, 0, 0);
            aZ0  = __builtin_amdgcn_mfma_f32_16x16x32_bf16(wzg, bx0, aZ0,  0, 0, 0);
            aZ1  = __builtin_amdgcn_mfma_f32_16x16x32_bf16(wzg, bx1, aZ1,  0, 0, 0);
            aXN0 = __builtin_amdgcn_mfma_f32_16x16x32_bf16(wn,  bx0, aXN0, 0, 0, 0);
            aXN1 = __builtin_amdgcn_mfma_f32_16x16x32_bf16(wn,  bx1, aXN1, 0, 0, 0);
            if (t == 1) {
                short8 r0 = *(const short8*)(whh + ((0 + mt) * 16 + arow) * 64 + grp * 8);
                short8 r1 = *(const short8*)(whh + ((0 + mt) * 16 + arow) * 64 + 32 + grp * 8);
                short8 z0 = *(const short8*)(whh + ((4 + mt) * 16 + arow) * 64 + grp * 8);
                short8 z1 = *(const short8*)(whh + ((4 + mt) * 16 + arow) * 64 + 32 + grp * 8);
                short8 n0 = *(const short8*)(whh + ((8 + mt) * 16 + arow) * 64 + grp * 8);
                short8 n1 = *(const short8*)(whh + ((8 + mt) * 16 + arow) * 64 + 32 + grp * 8);
                aR0  = __builtin_amdgcn_mfma_f32_16x16x32_bf16(r0, bh00, aR0, 0, 0, 0);
                aR0  = __builtin_amdgcn_mfma_f32_16x16x32_bf16(r1, bh01, aR0, 0, 0, 0);
                aR1  = __builtin_amdgcn_mfma_f32_16x16x32_bf16(r0, bh10, aR1, 0, 0, 0);
                aR1  = __builtin_amdgcn_mfma_f32_16x16x32_bf16(r1, bh11, aR1, 0, 0, 0);
                aZ0  = __builtin_amdgcn_mfma_f32_16x16x32_bf16(z0, bh00, aZ0, 0, 0, 0);
                aZ0  = __builtin_amdgcn_mfma_f32_16x16x32_bf16(z1, bh01, aZ0, 0, 0, 0);
                aZ1  = __builtin_amdgcn_mfma_f32_16x16x32_bf16(z0, bh10, aZ1, 0, 0, 0);
                aZ1  = __builtin_amdgcn_mfma_f32_16x16x32_bf16(z1, bh11, aZ1, 0, 0, 0);
                aHN0 = __builtin_amdgcn_mfma_f32_16x16x32_bf16(n0, bh00, aHN0, 0, 0, 0);
                aHN0 = __builtin_amdgcn_mfma_f32_16x16x32_bf16(n1, bh01, aHN0, 0, 0, 0);
                aHN1 = __builtin_amdgcn_mfma_f32_16x16x32_bf16(n0, bh10, aHN1, 0, 0, 0);
                aHN1 = __builtin_amdgcn_mfma_f32_16x16x32_bf16(n1, bh11, aHN1, 0, 0, 0);
            }
            // cell + stores, nt = 0,1
#pragma unroll
            for (int nt = 0; nt < 2; ++nt) {
                f32x4 aR = nt ? aR1 : aR0, aZ = nt ? aZ1 : aZ0;
                f32x4 aXN = nt ? aXN1 : aXN0, aHN = nt ? aHN1 : aHN0;
                char* Hrow = Hw + (nt * 16 + bcol) * 144 + mt * 32 + grp * 8;
                char* Arow = Aw + (nt * 16 + bcol) * 144 + mt * 32 + grp * 8;
                f32x4 hold = {0.f, 0.f, 0.f, 0.f};
                if (t == 1) {
                    uint2 hv = *(const uint2*)Hrow;
                    hold[0] = __uint_as_float(hv.x << 16);
                    hold[1] = __uint_as_float(hv.x & 0xffff0000u);
                    hold[2] = __uint_as_float(hv.y << 16);
                    hold[3] = __uint_as_float(hv.y & 0xffff0000u);
                }
                f32x4 h2;
#pragma unroll
                for (int r = 0; r < 4; ++r) {
                    float rg = sigf(aR[r]);
                    float zg = sigf(aZ[r]);
                    float nn = tanhfast(aXN[r] + rg * aHN[r]);
                    h2[r] = nn + zg * (hold[r] - nn);
                }
                uint2 pa;
                pa.x = (unsigned)f2bf(fmaxf(h2[0], 0.f)) | ((unsigned)f2bf(fmaxf(h2[1], 0.f)) << 16);
                pa.y = (unsigned)f2bf(fmaxf(h2[2], 0.f)) | ((unsigned)f2bf(fmaxf(h2[3], 0.f)) << 16);
                if (t == 0) {
                    uint2 ph;
                    ph.x = (unsigned)f2bf(h2[0]) | ((unsigned)f2bf(h2[1]) << 16);
                    ph.y = (unsigned)f2bf(h2[2]) | ((unsigned)f2bf(h2[3]) << 16);
                    *(uint2*)Hrow = ph;
                }
                *(uint2*)Arow = pa;
            }
        }
        // ---- MLP layer 1 (reads Aw act, writes m1 back to Aw) ----
        {
            const unsigned short* w1p = zb + 13824;
            short8 ba00 = *(const short8*)(Aw + bcol * 144 + grp * 16);
            short8 ba01 = *(const short8*)(Aw + bcol * 144 + 64 + grp * 16);
            short8 ba10 = *(const short8*)(Aw + (16 + bcol) * 144 + grp * 16);
            short8 ba11 = *(const short8*)(Aw + (16 + bcol) * 144 + 64 + grp * 16);
#pragma unroll
            for (int mt = 0; mt < 4; ++mt) {
                short8 wa = *(const short8*)(w1p + (mt * 16 + arow) * 64 + grp * 8);
                short8 wb2 = *(const short8*)(w1p + (mt * 16 + arow) * 64 + 32 + grp * 8);
                f32x4 bm = *(const f32x4*)&b1[n * 64 + mt * 16 + ch0];
                f32x4 m1a = bm, m1b = bm;
                m1a = __builtin_amdgcn_mfma_f32_16x16x32_bf16(wa,  ba00, m1a, 0, 0, 0);
                m1a = __builtin_amdgcn_mfma_f32_16x16x32_bf16(wb2, ba01, m1a, 0, 0, 0);
                m1b = __builtin_amdgcn_mfma_f32_16x16x32_bf16(wa,  ba10, m1b, 0, 0, 0);
                m1b = __builtin_amdgcn_mfma_f32_16x16x32_bf16(wb2, ba11, m1b, 0, 0, 0);
                uint2 p0, p1;
                p0.x = (unsigned)f2bf(fmaxf(m1a[0], 0.f)) | ((unsigned)f2bf(fmaxf(m1a[1], 0.f)) << 16);
                p0.y = (unsigned)f2bf(fmaxf(m1a[2], 0.f)) | ((unsigned)f2bf(fmaxf(m1a[3], 0.f)) << 16);
                p1.x = (unsigned)f2bf(fmaxf(m1b[0], 0.f)) | ((unsigned)f2bf(fmaxf(m1b[1], 0.f)) << 16);
                p1.y = (unsigned)f2bf(fmaxf(m1b[2], 0.f)) | ((unsigned)f2bf(fmaxf(m1b[3], 0.f)) << 16);
                *(uint2*)(Aw + bcol * 144 + mt * 32 + grp * 8) = p0;
                *(uint2*)(Aw + (16 + bcol) * 144 + mt * 32 + grp * 8) = p1;
            }
        }
        // ---- MLP layer 2 + head ----
        {
            const unsigned short* w2p = zb + 17920;
            short8 bm00 = *(const short8*)(Aw + bcol * 144 + grp * 16);
            short8 bm01 = *(const short8*)(Aw + bcol * 144 + 64 + grp * 16);
            short8 bm10 = *(const short8*)(Aw + (16 + bcol) * 144 + grp * 16);
            short8 bm11 = *(const short8*)(Aw + (16 + bcol) * 144 + 64 + grp * 16);
            float part0 = 0.f, part1 = 0.f;
#pragma unroll
            for (int mt = 0; mt < 4; ++mt) {
                short8 wa = *(const short8*)(w2p + (mt * 16 + arow) * 64 + grp * 8);
                short8 wb2 = *(const short8*)(w2p + (mt * 16 + arow) * 64 + 32 + grp * 8);
                f32x4 bm = *(const f32x4*)&b2[n * 64 + mt * 16 + ch0];
                f32x4 m2a = bm, m2b = bm;
                m2a = __builtin_amdgcn_mfma_f32_16x16x32_bf16(wa,  bm00, m2a, 0, 0, 0);
                m2a = __builtin_amdgcn_mfma_f32_16x16x32_bf16(wb2, bm01, m2a, 0, 0, 0);
                m2b = __builtin_amdgcn_mfma_f32_16x16x32_bf16(wa,  bm10, m2b, 0, 0, 0);
                m2b = __builtin_amdgcn_mfma_f32_16x16x32_bf16(wb2, bm11, m2b, 0, 0, 0);
                f32x4 w3v = *(const f32x4*)&W3[n * 64 + mt * 16 + ch0];
#pragma unroll
                for (int r = 0; r < 4; ++r) {
                    part0 += w3v[r] * fmaxf(m2a[r], 0.f);
                    part1 += w3v[r] * fmaxf(m2b[r], 0.f);
                }
            }
            part0 += __shfl_xor(part0, 16, 64);
            part0 += __shfl_xor(part0, 32, 64);
            part1 += __shfl_xor(part1, 16, 64);
            part1 += __shfl_xor(part1, 32, 64);
            if (l < 16) {
                float v0 = 3.f * (sigf(part0 + b3v) - 0.5f);
                float v1 = 3.f * (sigf(part1 + b3v) - 0.5f);
                p_flat[n * 4096 + (wb + bcol) * 2 + t] = v0;        // (n,b,t)-major
                p_flat[n * 4096 + (wb + 16 + bcol) * 2 + t] = v1;
            }
        }
    }
}

// ---------------------------------------------------------------------------
// Critic + p-last gather: grid 512, block 256, wave per batch row.
// Only zone 99 contributes; neighbors {99,89,0,0,98}.
// ---------------------------------------------------------------------------
__global__ __launch_bounds__(256, 2)
void critic_kernel(const float* __restrict__ x, const float* __restrict__ p_flat,
                   const float* __restrict__ lmW1, const float* __restrict__ lmb1,
                   const float* __restrict__ lmW2, const float* __restrict__ lmb2,
                   const float* __restrict__ lmW3, const float* __restrict__ lmb3,
                   const float* __restrict__ scWih, const float* __restrict__ scWhh,
                   const float* __restrict__ scbih, const float* __restrict__ scbhh,
                   const float* __restrict__ scW1, const float* __restrict__ scb1,
                   const float* __restrict__ scW2, const float* __restrict__ scb2,
                   const float* __restrict__ scW3, const float* __restrict__ scb3,
                   float* __restrict__ out)
{
    __shared__ float sxi[4][72];
    __shared__ float shh[4][68];
    __shared__ float sab[4][68];
    __shared__ float sc1[4][68];
    __shared__ float sf1[4][132];

    const int tid = threadIdx.x;
    const int wid = tid >> 6;
    const int lane = tid & 63;
    const int b = blockIdx.x * 4 + wid;

    for (int idx = lane; idx < 72; idx += 64) {
        int t = idx / 36, c = idx - t * 36;
        float v = 0.f;
        if (c < 35) {
            int g = c / 7, e = c - g * 7;
            int z = (g == 0) ? 99 : (g == 1) ? 89 : (g == 4) ? 98 : -1;
            if (z >= 0)
                v = (e < 6) ? x[((size_t)b * 2 + t) * 600 + z * 6 + e]
                            : p_flat[b * 200 + t * 100 + z];
        }
        sxi[wid][idx] = v;
    }
    __syncthreads();

    float cg00 = scbih[lane], cg01 = scbih[lane + 64], cg02 = scbih[lane + 128];
    float cg10 = cg00, cg11 = cg01, cg12 = cg02;
    for (int c = 0; c < 35; ++c) {
        float w0 = scWih[lane * 35 + c];
        float w1 = scWih[(lane + 64) * 35 + c];
        float w2 = scWih[(lane + 128) * 35 + c];
        float x0 = sxi[wid][c], x1 = sxi[wid][36 + c];
        cg00 += w0 * x0; cg01 += w1 * x0; cg02 += w2 * x0;
        cg10 += w0 * x1; cg11 += w1 * x1; cg12 += w2 * x1;
    }
    const float bhr = scbhh[lane], bhz = scbhh[lane + 64], bhn = scbhh[lane + 128];
    float r  = 1.f / (1.f + expf(-(cg00 + bhr)));
    float zg = 1.f / (1.f + expf(-(cg01 + bhz)));
    float nn = tanhf(cg02 + r * bhn);
    float hj = (1.f - zg) * nn;
    shh[wid][lane] = hj;
    __syncthreads();
    float ghr = bhr, ghz = bhz, ghn = bhn;
    for (int kc = 0; kc < 16; ++kc) {
        float4 wr  = *(const float4*)&scWhh[lane * 64 + kc * 4];
        float4 wzv = *(const float4*)&scWhh[(lane + 64) * 64 + kc * 4];
        float4 wn  = *(const float4*)&scWhh[(lane + 128) * 64 + kc * 4];
        float4 hv  = *(const float4*)&shh[wid][kc * 4];
        ghr += wr.x * hv.x + wr.y * hv.y + wr.z * hv.z + wr.w * hv.w;
        ghz += wzv.x * hv.x + wzv.y * hv.y + wzv.z * hv.z + wzv.w * hv.w;
        ghn += wn.x * hv.x + wn.y * hv.y + wn.z * hv.z + wn.w * hv.w;
    }
    r  = 1.f / (1.f + expf(-(cg10 + ghr)));
    zg = 1.f / (1.f + expf(-(cg11 + ghz)));
    nn = tanhf(cg12 + r * ghn);
    hj = (1.f - zg) * nn + zg * hj;
    sab[wid][lane] = fmaxf(hj, 0.f);
    __syncthreads();
    float acc = scb1[lane];
    for (int kc = 0; kc < 16; ++kc) {
        float4 wv = *(const float4*)&scW1[lane * 64 + kc * 4];
        float4 av = *(const float4*)&sab[wid][kc * 4];
        acc += wv.x * av.x + wv.y * av.y + wv.z * av.z + wv.w * av.w;
    }
    sc1[wid][lane] = fmaxf(acc, 0.f);
    __syncthreads();
    float acc2 = scb2[lane];
    for (int kc = 0; kc < 16; ++kc) {
        float4 wv = *(const float4*)&scW2[lane * 64 + kc * 4];
        float4 av = *(const float4*)&sc1[wid][kc * 4];
        acc2 += wv.x * av.x + wv.y * av.y + wv.z * av.z + wv.w * av.w;
    }
    float qpart = scW3[lane] * fmaxf(acc2, 0.f);
    float f1a = lmb1[lane], f1c = lmb1[lane + 64];
    for (int c = 0; c < 35; ++c) {
        float xv = sxi[wid][36 + c];
        f1a += lmW1[lane * 35 + c] * xv;
        f1c += lmW1[(lane + 64) * 35 + c] * xv;
    }
    sf1[wid][lane] = fmaxf(f1a, 0.f);
    sf1[wid][lane + 64] = fmaxf(f1c, 0.f);
    __syncthreads();
    float f2a = lmb2[lane], f2c = lmb2[lane + 64];
    for (int kc = 0; kc < 32; ++kc) {
        float4 fv = *(const float4*)&sf1[wid][kc * 4];
        float4 wa = *(const float4*)&lmW2[lane * 128 + kc * 4];
        float4 wc = *(const float4*)&lmW2[(lane + 64) * 128 + kc * 4];
        f2a += wa.x * fv.x + wa.y * fv.y + wa.z * fv.z + wa.w * fv.w;
        f2c += wc.x * fv.x + wc.y * fv.y + wc.z * fv.z + wc.w * fv.w;
    }
    float fpart = lmW3[lane] * fmaxf(f2a, 0.f) + lmW3[lane + 64] * fmaxf(f2c, 0.f);

    float tot = qpart + fpart;
    for (int m = 32; m > 0; m >>= 1) tot += __shfl_xor(tot, m, 64);
    if (lane == 0) out[204800 + b] = tot + scb3[0] + lmb3[0];

    for (int l2 = lane; l2 < 100; l2 += 64)
        out[b * 100 + l2] = p_flat[b * 200 + 100 + l2];
}

extern "C" void kernel_launch(void* const* d_in, const int* in_sizes, int n_in,
                              void* d_out, int out_size, void* d_ws, size_t ws_size,
                              hipStream_t stream) {
    const float* x     = (const float*)d_in[0];
    const float* aWih  = (const float*)d_in[1];
    const float* aWhh  = (const float*)d_in[2];
    const float* abih  = (const float*)d_in[3];
    const float* abhh  = (const float*)d_in[4];
    const float* aW1   = (const float*)d_in[5];
    const float* ab1   = (const float*)d_in[6];
    const float* aW2   = (const float*)d_in[7];
    const float* ab2   = (const float*)d_in[8];
    const float* aW3   = (const float*)d_in[9];
    const float* ab3   = (const float*)d_in[10];
    const float* lmW1  = (const float*)d_in[11];
    const float* lmb1  = (const float*)d_in[12];
    const float* lmW2  = (const float*)d_in[13];
    const float* lmb2  = (const float*)d_in[14];
    const float* lmW3  = (const float*)d_in[15];
    const float* lmb3  = (const float*)d_in[16];
    const float* scWih = (const float*)d_in[17];
    const float* scWhh = (const float*)d_in[18];
    const float* scbih = (const float*)d_in[19];
    const float* scbhh = (const float*)d_in[20];
    const float* scW1  = (const float*)d_in[21];
    const float* scb1  = (const float*)d_in[22];
    const float* scW2  = (const float*)d_in[23];
    const float* scb2  = (const float*)d_in[24];
    const float* scW3  = (const float*)d_in[25];
    const float* scb3  = (const float*)d_in[26];
    float* out = (float*)d_out;
    float* p_flat = (float*)d_ws;                                          // 1.6 MB
    unsigned short* wz = (unsigned short*)((char*)d_ws + WS_W_OFF_BYTES);  // 4.4 MB

    convert_kernel<<<dim3((100 * ZW + 255) / 256), 256, 0, stream>>>(
        aWih, aWhh, aW1, aW2, wz);

    actor_kernel<<<dim3(1600), 256, 0, stream>>>(
        x, wz, abih, abhh, ab1, ab2, aW3, ab3, p_flat);

    critic_kernel<<<dim3(512), 256, 0, stream>>>(
        x, p_flat, lmW1, lmb1, lmW2, lmb2, lmW3, lmb3,
        scWih, scWhh, scbih, scbhh, scW1, scb1, scW2, scb2, scW3, scb3, out);
}

// Round 7
// 119.062 us; speedup vs baseline: 1.7326x; 1.6659x over previous
//
#include <hip/hip_runtime.h>
#include <hip/hip_bf16.h>

typedef __attribute__((ext_vector_type(8))) short short8;
typedef __attribute__((ext_vector_type(4))) float f32x4;

// ---- actor LDS layout (bytes); total 131072 (128 KB, 1 block/CU) ----
#define OFF_WIH 0        // [192][8] shorts = 3072
#define OFF_WHH 3072     // [192][72] shorts (64 + 8 pad) = 27648
#define OFF_W1  30720    // [64][72] = 9216
#define OFF_W2  39936    // 9216
#define OFF_X   49152    // [2 t][256 b][8 k] shorts = 8192
#define OFF_H   57344    // [16 w][16 b][72 ch] shorts = 36864
#define OFF_A   94208    // 36864 -> ends 131072
#define LDS_TOTAL 131072

__device__ __forceinline__ unsigned short f2bf(float f) {
    unsigned u = __float_as_uint(f);
    return (unsigned short)((u + 0x7FFFu + ((u >> 16) & 1u)) >> 16);  // RNE
}
__device__ __forceinline__ float sigf(float x) {
    return __builtin_amdgcn_rcpf(1.f + __builtin_amdgcn_exp2f(-1.4426950408889634f * x));
}
__device__ __forceinline__ float tanhfast(float y) {
    return 1.f - 2.f * __builtin_amdgcn_rcpf(1.f + __builtin_amdgcn_exp2f(2.8853900817779268f * y));
}

// ---------------------------------------------------------------------------
// Actor: grid 800 = 100 zones x 8 chunks(256 batches), block 1024 = 16 waves.
// All weights staged f32->bf16 into LDS once (ONE __syncthreads), then each
// wave independently runs its 16-batch tile: LDS A-frags + LDS B-frags + MFMA.
// Weight rows stride 144 B (72 shorts) -> banks spread (<=8-way).
// Zero-frag trick for gx (K=32, only cols 0..7 real; grp!=0 lanes use zeros).
// C/D: col=lane&15 (batch), row=(lane>>4)*4+reg (channel)  [m89-verified].
// Biases read from global (L2-hot f32x4) as in round 3 (VGPR-light, proven).
// ---------------------------------------------------------------------------
__global__ __launch_bounds__(1024, 4)
void actor_kernel(const float* __restrict__ x, const float* __restrict__ Wih,
                  const float* __restrict__ Whh, const float* __restrict__ bih,
                  const float* __restrict__ bhh, const float* __restrict__ W1,
                  const float* __restrict__ b1, const float* __restrict__ W2,
                  const float* __restrict__ b2, const float* __restrict__ W3,
                  const float* __restrict__ b3, float* __restrict__ p_flat)
{
    extern __shared__ char sm[];
    unsigned short* sWih = (unsigned short*)(sm + OFF_WIH);
    unsigned short* sWhh = (unsigned short*)(sm + OFF_WHH);
    unsigned short* sW1  = (unsigned short*)(sm + OFF_W1);
    unsigned short* sW2  = (unsigned short*)(sm + OFF_W2);

    const int tid   = threadIdx.x;
    const int n     = blockIdx.x >> 3;       // zone
    const int chunk = blockIdx.x & 7;        // 256-batch chunk
    const int w     = tid >> 6;
    const int l     = tid & 63;
    const int bcol  = l & 15;
    const int grp   = l >> 4;
    const int arow  = bcol;
    const int ch0   = grp * 4;

    // ---- cooperative staging: weights f32 -> bf16 LDS ----
    {
        const float* g = Whh + n * 12288;
        for (int i = tid; i < 12288; i += 1024)
            sWhh[(i >> 6) * 72 + (i & 63)] = f2bf(g[i]);
        const float* g1 = W1 + n * 4096;
        const float* g2 = W2 + n * 4096;
        for (int i = tid; i < 4096; i += 1024) {
            int p = (i >> 6) * 72 + (i & 63);
            sW1[p] = f2bf(g1[i]);
            sW2[p] = f2bf(g2[i]);
        }
        const float* gih = Wih + n * 1152;
        for (int i = tid; i < 1536; i += 1024) {
            int row = i >> 3, k = i & 7;
            sWih[i] = (k < 6) ? f2bf(gih[row * 6 + k]) : (unsigned short)0;
        }
        if (tid < 512) {   // x: [2t][256b][8k] bf16, rows padded to 16 B
            int t = tid >> 8, b = tid & 255;
            const float* xr = x + (size_t)(chunk * 256 + b) * 1200 + t * 600 + n * 6;
            float2 v0 = *(const float2*)xr;
            float2 v1 = *(const float2*)(xr + 2);
            float2 v2 = *(const float2*)(xr + 4);
            uint4 pk;
            pk.x = (unsigned)f2bf(v0.x) | ((unsigned)f2bf(v0.y) << 16);
            pk.y = (unsigned)f2bf(v1.x) | ((unsigned)f2bf(v1.y) << 16);
            pk.z = (unsigned)f2bf(v2.x) | ((unsigned)f2bf(v2.y) << 16);
            pk.w = 0u;
            *(uint4*)(sm + OFF_X + (t * 256 + b) * 16) = pk;
        }
    }
    __syncthreads();   // the only barrier

    char* Hw = sm + OFF_H + w * 2304;      // [16 b][72 ch] shorts, wave-private
    char* Aw = sm + OFF_A + w * 2304;

    const float* bihz = bih + n * 192;
    const float* bhhz = bhh + n * 192;
    const float b3v = b3[n];
    const short8 zfrag = {0, 0, 0, 0, 0, 0, 0, 0};

    for (int t = 0; t < 2; ++t) {
        // B-frag for gx (zero unless grp==0; K cols 8..31 all zero)
        short8 bx = zfrag;
        if (grp == 0)
            bx = *(const short8*)(sm + OFF_X + (t * 256 + w * 16 + bcol) * 16);
        short8 bh0, bh1;
        if (t == 1) {
            bh0 = *(const short8*)(Hw + bcol * 144 + grp * 16);
            bh1 = *(const short8*)(Hw + bcol * 144 + 64 + grp * 16);
        }
        // ---- GRU gates + cell, per M-tile ----
#pragma unroll
        for (int mt = 0; mt < 4; ++mt) {
            const int ch = mt * 16 + ch0;
            f32x4 aR  = *(const f32x4*)&bihz[ch]      + *(const f32x4*)&bhhz[ch];
            f32x4 aZ  = *(const f32x4*)&bihz[64 + ch] + *(const f32x4*)&bhhz[64 + ch];
            f32x4 aXN = *(const f32x4*)&bihz[128 + ch];
            f32x4 aHN = *(const f32x4*)&bhhz[128 + ch];
            short8 wr = zfrag, wzg = zfrag, wn = zfrag;
            if (grp == 0) {
                wr  = *(const short8*)(sWih + ((0 + mt) * 16 + arow) * 8);
                wzg = *(const short8*)(sWih + ((4 + mt) * 16 + arow) * 8);
                wn  = *(const short8*)(sWih + ((8 + mt) * 16 + arow) * 8);
            }
            aR  = __builtin_amdgcn_mfma_f32_16x16x32_bf16(wr,  bx, aR,  0, 0, 0);
            aZ  = __builtin_amdgcn_mfma_f32_16x16x32_bf16(wzg, bx, aZ,  0, 0, 0);
            aXN = __builtin_amdgcn_mfma_f32_16x16x32_bf16(wn,  bx, aXN, 0, 0, 0);
            if (t == 1) {
                aR  = __builtin_amdgcn_mfma_f32_16x16x32_bf16(
                          *(const short8*)(sWhh + ((0 + mt) * 16 + arow) * 72 + grp * 8), bh0, aR, 0, 0, 0);
                aR  = __builtin_amdgcn_mfma_f32_16x16x32_bf16(
                          *(const short8*)(sWhh + ((0 + mt) * 16 + arow) * 72 + 32 + grp * 8), bh1, aR, 0, 0, 0);
                aZ  = __builtin_amdgcn_mfma_f32_16x16x32_bf16(
                          *(const short8*)(sWhh + ((4 + mt) * 16 + arow) * 72 + grp * 8), bh0, aZ, 0, 0, 0);
                aZ  = __builtin_amdgcn_mfma_f32_16x16x32_bf16(
                          *(const short8*)(sWhh + ((4 + mt) * 16 + arow) * 72 + 32 + grp * 8), bh1, aZ, 0, 0, 0);
                aHN = __builtin_amdgcn_mfma_f32_16x16x32_bf16(
                          *(const short8*)(sWhh + ((8 + mt) * 16 + arow) * 72 + grp * 8), bh0, aHN, 0, 0, 0);
                aHN = __builtin_amdgcn_mfma_f32_16x16x32_bf16(
                          *(const short8*)(sWhh + ((8 + mt) * 16 + arow) * 72 + 32 + grp * 8), bh1, aHN, 0, 0, 0);
            }
            // cell
            f32x4 hold = {0.f, 0.f, 0.f, 0.f};
            if (t == 1) {
                uint2 hv = *(const uint2*)(Hw + bcol * 144 + mt * 32 + grp * 8);
                hold[0] = __uint_as_float(hv.x << 16);
                hold[1] = __uint_as_float(hv.x & 0xffff0000u);
                hold[2] = __uint_as_float(hv.y << 16);
                hold[3] = __uint_as_float(hv.y & 0xffff0000u);
            }
            f32x4 h2;
#pragma unroll
            for (int r = 0; r < 4; ++r) {
                float rg = sigf(aR[r]);
                float zg = sigf(aZ[r]);
                float nn = tanhfast(aXN[r] + rg * aHN[r]);
                h2[r] = nn + zg * (hold[r] - nn);
            }
            uint2 pa;
            pa.x = (unsigned)f2bf(fmaxf(h2[0], 0.f)) | ((unsigned)f2bf(fmaxf(h2[1], 0.f)) << 16);
            pa.y = (unsigned)f2bf(fmaxf(h2[2], 0.f)) | ((unsigned)f2bf(fmaxf(h2[3], 0.f)) << 16);
            if (t == 0) {
                uint2 ph;
                ph.x = (unsigned)f2bf(h2[0]) | ((unsigned)f2bf(h2[1]) << 16);
                ph.y = (unsigned)f2bf(h2[2]) | ((unsigned)f2bf(h2[3]) << 16);
                *(uint2*)(Hw + bcol * 144 + mt * 32 + grp * 8) = ph;
            }
            *(uint2*)(Aw + bcol * 144 + mt * 32 + grp * 8) = pa;
        }
        // ---- MLP layer 1 (reads Aw act, writes m1 back to Aw) ----
        {
            short8 ba0 = *(const short8*)(Aw + bcol * 144 + grp * 16);
            short8 ba1 = *(const short8*)(Aw + bcol * 144 + 64 + grp * 16);
            f32x4 m1o[4];
#pragma unroll
            for (int mt = 0; mt < 4; ++mt) {
                f32x4 m1 = *(const f32x4*)&b1[n * 64 + mt * 16 + ch0];
                m1 = __builtin_amdgcn_mfma_f32_16x16x32_bf16(
                         *(const short8*)(sW1 + (mt * 16 + arow) * 72 + grp * 8), ba0, m1, 0, 0, 0);
                m1 = __builtin_amdgcn_mfma_f32_16x16x32_bf16(
                         *(const short8*)(sW1 + (mt * 16 + arow) * 72 + 32 + grp * 8), ba1, m1, 0, 0, 0);
                m1o[mt] = m1;
            }
#pragma unroll
            for (int mt = 0; mt < 4; ++mt) {
                uint2 pm;
                pm.x = (unsigned)f2bf(fmaxf(m1o[mt][0], 0.f)) | ((unsigned)f2bf(fmaxf(m1o[mt][1], 0.f)) << 16);
                pm.y = (unsigned)f2bf(fmaxf(m1o[mt][2], 0.f)) | ((unsigned)f2bf(fmaxf(m1o[mt][3], 0.f)) << 16);
                *(uint2*)(Aw + bcol * 144 + mt * 32 + grp * 8) = pm;
            }
        }
        // ---- MLP layer 2 + head ----
        {
            short8 bm0 = *(const short8*)(Aw + bcol * 144 + grp * 16);
            short8 bm1 = *(const short8*)(Aw + bcol * 144 + 64 + grp * 16);
            float part = 0.f;
#pragma unroll
            for (int mt = 0; mt < 4; ++mt) {
                f32x4 m2 = *(const f32x4*)&b2[n * 64 + mt * 16 + ch0];
                m2 = __builtin_amdgcn_mfma_f32_16x16x32_bf16(
                         *(const short8*)(sW2 + (mt * 16 + arow) * 72 + grp * 8), bm0, m2, 0, 0, 0);
                m2 = __builtin_amdgcn_mfma_f32_16x16x32_bf16(
                         *(const short8*)(sW2 + (mt * 16 + arow) * 72 + 32 + grp * 8), bm1, m2, 0, 0, 0);
                f32x4 w3v = *(const f32x4*)&W3[n * 64 + mt * 16 + ch0];
#pragma unroll
                for (int r = 0; r < 4; ++r)
                    part += w3v[r] * fmaxf(m2[r], 0.f);
            }
            part += __shfl_xor(part, 16, 64);
            part += __shfl_xor(part, 32, 64);
            float val = 3.f * (sigf(part + b3v) - 0.5f);
            if (l < 16)
                p_flat[n * 4096 + (chunk * 256 + w * 16 + bcol) * 2 + t] = val;  // (n,b,t)-major
        }
    }
}

// ---------------------------------------------------------------------------
// Critic + p-last gather: grid 512, block 256, wave per batch row.
// Only zone 99 contributes; neighbors {99,89,0,0,98}.
// ---------------------------------------------------------------------------
__global__ __launch_bounds__(256, 2)
void critic_kernel(const float* __restrict__ x, const float* __restrict__ p_flat,
                   const float* __restrict__ lmW1, const float* __restrict__ lmb1,
                   const float* __restrict__ lmW2, const float* __restrict__ lmb2,
                   const float* __restrict__ lmW3, const float* __restrict__ lmb3,
                   const float* __restrict__ scWih, const float* __restrict__ scWhh,
                   const float* __restrict__ scbih, const float* __restrict__ scbhh,
                   const float* __restrict__ scW1, const float* __restrict__ scb1,
                   const float* __restrict__ scW2, const float* __restrict__ scb2,
                   const float* __restrict__ scW3, const float* __restrict__ scb3,
                   float* __restrict__ out)
{
    __shared__ float sxi[4][72];
    __shared__ float shh[4][68];
    __shared__ float sab[4][68];
    __shared__ float sc1[4][68];
    __shared__ float sf1[4][132];

    const int tid = threadIdx.x;
    const int wid = tid >> 6;
    const int lane = tid & 63;
    const int b = blockIdx.x * 4 + wid;

    for (int idx = lane; idx < 72; idx += 64) {
        int t = idx / 36, c = idx - t * 36;
        float v = 0.f;
        if (c < 35) {
            int g = c / 7, e = c - g * 7;
            int z = (g == 0) ? 99 : (g == 1) ? 89 : (g == 4) ? 98 : -1;
            if (z >= 0)
                v = (e < 6) ? x[((size_t)b * 2 + t) * 600 + z * 6 + e]
                            : p_flat[b * 200 + t * 100 + z];
        }
        sxi[wid][idx] = v;
    }
    __syncthreads();

    float cg00 = scbih[lane], cg01 = scbih[lane + 64], cg02 = scbih[lane + 128];
    float cg10 = cg00, cg11 = cg01, cg12 = cg02;
    for (int c = 0; c < 35; ++c) {
        float w0 = scWih[lane * 35 + c];
        float w1 = scWih[(lane + 64) * 35 + c];
        float w2 = scWih[(lane + 128) * 35 + c];
        float x0 = sxi[wid][c], x1 = sxi[wid][36 + c];
        cg00 += w0 * x0; cg01 += w1 * x0; cg02 += w2 * x0;
        cg10 += w0 * x1; cg11 += w1 * x1; cg12 += w2 * x1;
    }
    const float bhr = scbhh[lane], bhz = scbhh[lane + 64], bhn = scbhh[lane + 128];
    float r  = 1.f / (1.f + expf(-(cg00 + bhr)));
    float zg = 1.f / (1.f + expf(-(cg01 + bhz)));
    float nn = tanhf(cg02 + r * bhn);
    float hj = (1.f - zg) * nn;
    shh[wid][lane] = hj;
    __syncthreads();
    float ghr = bhr, ghz = bhz, ghn = bhn;
    for (int kc = 0; kc < 16; ++kc) {
        float4 wr  = *(const float4*)&scWhh[lane * 64 + kc * 4];
        float4 wzv = *(const float4*)&scWhh[(lane + 64) * 64 + kc * 4];
        float4 wn  = *(const float4*)&scWhh[(lane + 128) * 64 + kc * 4];
        float4 hv  = *(const float4*)&shh[wid][kc * 4];
        ghr += wr.x * hv.x + wr.y * hv.y + wr.z * hv.z + wr.w * hv.w;
        ghz += wzv.x * hv.x + wzv.y * hv.y + wzv.z * hv.z + wzv.w * hv.w;
        ghn += wn.x * hv.x + wn.y * hv.y + wn.z * hv.z + wn.w * hv.w;
    }
    r  = 1.f / (1.f + expf(-(cg10 + ghr)));
    zg = 1.f / (1.f + expf(-(cg11 + ghz)));
    nn = tanhf(cg12 + r * ghn);
    hj = (1.f - zg) * nn + zg * hj;
    sab[wid][lane] = fmaxf(hj, 0.f);
    __syncthreads();
    float acc = scb1[lane];
    for (int kc = 0; kc < 16; ++kc) {
        float4 wv = *(const float4*)&scW1[lane * 64 + kc * 4];
        float4 av = *(const float4*)&sab[wid][kc * 4];
        acc += wv.x * av.x + wv.y * av.y + wv.z * av.z + wv.w * av.w;
    }
    sc1[wid][lane] = fmaxf(acc, 0.f);
    __syncthreads();
    float acc2 = scb2[lane];
    for (int kc = 0; kc < 16; ++kc) {
        float4 wv = *(const float4*)&scW2[lane * 64 + kc * 4];
        float4 av = *(const float4*)&sc1[wid][kc * 4];
        acc2 += wv.x * av.x + wv.y * av.y + wv.z * av.z + wv.w * av.w;
    }
    float qpart = scW3[lane] * fmaxf(acc2, 0.f);
    float f1a = lmb1[lane], f1c = lmb1[lane + 64];
    for (int c = 0; c < 35; ++c) {
        float xv = sxi[wid][36 + c];
        f1a += lmW1[lane * 35 + c] * xv;
        f1c += lmW1[(lane + 64) * 35 + c] * xv;
    }
    sf1[wid][lane] = fmaxf(f1a, 0.f);
    sf1[wid][lane + 64] = fmaxf(f1c, 0.f);
    __syncthreads();
    float f2a = lmb2[lane], f2c = lmb2[lane + 64];
    for (int kc = 0; kc < 32; ++kc) {
        float4 fv = *(const float4*)&sf1[wid][kc * 4];
        float4 wa = *(const float4*)&lmW2[lane * 128 + kc * 4];
        float4 wc = *(const float4*)&lmW2[(lane + 64) * 128 + kc * 4];
        f2a += wa.x * fv.x + wa.y * fv.y + wa.z * fv.z + wa.w * fv.w;
        f2c += wc.x * fv.x + wc.y * fv.y + wc.z * fv.z + wc.w * fv.w;
    }
    float fpart = lmW3[lane] * fmaxf(f2a, 0.f) + lmW3[lane + 64] * fmaxf(f2c, 0.f);

    float tot = qpart + fpart;
    for (int m = 32; m > 0; m >>= 1) tot += __shfl_xor(tot, m, 64);
    if (lane == 0) out[204800 + b] = tot + scb3[0] + lmb3[0];

    for (int l2 = lane; l2 < 100; l2 += 64)
        out[b * 100 + l2] = p_flat[b * 200 + 100 + l2];
}

extern "C" void kernel_launch(void* const* d_in, const int* in_sizes, int n_in,
                              void* d_out, int out_size, void* d_ws, size_t ws_size,
                              hipStream_t stream) {
    const float* x     = (const float*)d_in[0];
    const float* aWih  = (const float*)d_in[1];
    const float* aWhh  = (const float*)d_in[2];
    const float* abih  = (const float*)d_in[3];
    const float* abhh  = (const float*)d_in[4];
    const float* aW1   = (const float*)d_in[5];
    const float* ab1   = (const float*)d_in[6];
    const float* aW2   = (const float*)d_in[7];
    const float* ab2   = (const float*)d_in[8];
    const float* aW3   = (const float*)d_in[9];
    const float* ab3   = (const float*)d_in[10];
    const float* lmW1  = (const float*)d_in[11];
    const float* lmb1  = (const float*)d_in[12];
    const float* lmW2  = (const float*)d_in[13];
    const float* lmb2  = (const float*)d_in[14];
    const float* lmW3  = (const float*)d_in[15];
    const float* lmb3  = (const float*)d_in[16];
    const float* scWih = (const float*)d_in[17];
    const float* scWhh = (const float*)d_in[18];
    const float* scbih = (const float*)d_in[19];
    const float* scbhh = (const float*)d_in[20];
    const float* scW1  = (const float*)d_in[21];
    const float* scb1  = (const float*)d_in[22];
    const float* scW2  = (const float*)d_in[23];
    const float* scb2  = (const float*)d_in[24];
    const float* scW3  = (const float*)d_in[25];
    const float* scb3  = (const float*)d_in[26];
    float* out = (float*)d_out;
    float* p_flat = (float*)d_ws;   // 409600 f32 = 1.6 MB

    hipFuncSetAttribute((const void*)actor_kernel,
                        hipFuncAttributeMaxDynamicSharedMemorySize, LDS_TOTAL);

    actor_kernel<<<dim3(800), 1024, LDS_TOTAL, stream>>>(
        x, aWih, aWhh, abih, abhh, aW1, ab1, aW2, ab2, aW3, ab3, p_flat);

    critic_kernel<<<dim3(512), 256, 0, stream>>>(
        x, p_flat, lmW1, lmb1, lmW2, lmb2, lmW3, lmb3,
        scWih, scWhh, scbih, scbhh, scW1, scb1, scW2, scb2, scW3, scb3, out);
}

// Round 8
// 111.261 us; speedup vs baseline: 1.8541x; 1.0701x over previous
//
#include <hip/hip_runtime.h>
#include <hip/hip_bf16.h>

typedef __attribute__((ext_vector_type(8))) short short8;
typedef __attribute__((ext_vector_type(4))) float f32x4;

// ---- actor LDS layout (bytes); total 80896 (79 KB -> 2 blocks/CU) ----
// All 2D tiles: row stride 64 shorts (128 B), XOR-swizzled granules:
//   byte(row, b) = row*128 + ((b & ~15) ^ ((row&7)<<4)) + (b & 15)
#define OFF_WIH 0        // [192][8] shorts, linear 16B rows = 3072
#define OFF_WHH 3072     // [192][64] swz = 24576 -> 27648
#define OFF_W1  27648    // [64][64] swz = 8192 -> 35840
#define OFF_W2  35840    // 8192 -> 44032
#define OFF_X   44032    // [2t][128b][8k] shorts linear = 4096 -> 48128
#define OFF_H   48128    // [8w][16b][64ch] swz = 16384 -> 64512
#define OFF_A   64512    // 16384 -> 80896   (OFF_A - OFF_H = 16384)
#define LDS_TOTAL 80896

__device__ __forceinline__ unsigned pkbf(float a, float b) {
    __hip_bfloat162 h = __float22bfloat162_rn(make_float2(a, b));  // v_cvt_pk_bf16_f32
    return *reinterpret_cast<unsigned*>(&h);
}
__device__ __forceinline__ float sigf(float x) {
    return __builtin_amdgcn_rcpf(1.f + __builtin_amdgcn_exp2f(-1.4426950408889634f * x));
}
__device__ __forceinline__ float tanhfast(float y) {
    return 1.f - 2.f * __builtin_amdgcn_rcpf(1.f + __builtin_amdgcn_exp2f(2.8853900817779268f * y));
}

// ---------------------------------------------------------------------------
// Actor: grid 1600 = 100 zones x 16 chunks(128 batches), block 512 = 8 waves.
// 79 KB LDS -> 2 blocks/CU co-resident (staging of one overlaps compute of
// the other). Weights staged once (ONE __syncthreads), wave-private H/A tiles.
// XOR-swizzled rows: A-frag reads are provably bank-conflict-free.
// h carried in fp32 regs (hp[4], statically indexed); H tile only feeds the
// bh B-frag transpose at t=1.
// C/D: col=lane&15 (batch), row=(lane>>4)*4+reg (channel)  [m89-verified].
// ---------------------------------------------------------------------------
__global__ __launch_bounds__(512, 4)
void actor_kernel(const float* __restrict__ x, const float* __restrict__ Wih,
                  const float* __restrict__ Whh, const float* __restrict__ bih,
                  const float* __restrict__ bhh, const float* __restrict__ W1,
                  const float* __restrict__ b1, const float* __restrict__ W2,
                  const float* __restrict__ b2, const float* __restrict__ W3,
                  const float* __restrict__ b3, float* __restrict__ p_flat)
{
    extern __shared__ char sm[];
    const int tid   = threadIdx.x;
    const int n     = blockIdx.x >> 4;       // zone
    const int chunk = blockIdx.x & 15;       // 128-batch chunk
    const int w     = tid >> 6;
    const int l     = tid & 63;
    const int bcol  = l & 15;
    const int grp   = l >> 4;
    const int arow  = bcol;
    const int ch0   = grp * 4;

    // ---- cooperative staging: f32 -> bf16 packed b32 writes, swizzled ----
    {
        const float* g = Whh + n * 12288;
        for (int i = tid; i < 6144; i += 512) {          // dword pairs
            int row = i >> 5, j = i & 31;                // j-th pair in row
            float2 v = *(const float2*)(g + row * 64 + j * 2);
            *(unsigned*)(sm + OFF_WHH + row * 128 + ((j * 4) ^ ((row & 7) << 4))) = pkbf(v.x, v.y);
        }
        const float* g1 = W1 + n * 4096;
        const float* g2 = W2 + n * 4096;
        for (int i = tid; i < 2048; i += 512) {
            int row = i >> 5, j = i & 31;
            int off = row * 128 + ((j * 4) ^ ((row & 7) << 4));
            float2 v1 = *(const float2*)(g1 + row * 64 + j * 2);
            float2 v2 = *(const float2*)(g2 + row * 64 + j * 2);
            *(unsigned*)(sm + OFF_W1 + off) = pkbf(v1.x, v1.y);
            *(unsigned*)(sm + OFF_W2 + off) = pkbf(v2.x, v2.y);
        }
        const float* gih = Wih + n * 1152;
        for (int i = tid; i < 768; i += 512) {           // [192][8]: pairs
            int row = i >> 2, j = i & 3;
            float a = (2 * j < 6)     ? gih[row * 6 + 2 * j]     : 0.f;
            float b = (2 * j + 1 < 6) ? gih[row * 6 + 2 * j + 1] : 0.f;
            *(unsigned*)(sm + OFF_WIH + row * 16 + j * 4) = pkbf(a, b);
        }
        if (tid < 256) {                                  // x rows: [2t][128b]
            int t = tid >> 7, b = tid & 127;
            const float* xr = x + (size_t)(chunk * 128 + b) * 1200 + t * 600 + n * 6;
            uint4 pk;
            pk.x = pkbf(xr[0], xr[1]);
            pk.y = pkbf(xr[2], xr[3]);
            pk.z = pkbf(xr[4], xr[5]);
            pk.w = 0u;
            *(uint4*)(sm + OFF_X + (t * 128 + b) * 16) = pk;
        }
    }
    __syncthreads();   // the only barrier

    // ---- per-lane swizzled bases (immediate offsets thereafter) ----
    const int a7  = arow & 7;
    const int gsz = (grp ^ a7) << 4;
    const char* whhA = sm + OFF_WHH + arow * 128 + gsz;
    const char* whhB = sm + OFF_WHH + arow * 128 + (gsz ^ 64);
    const char* w1A  = sm + OFF_W1  + arow * 128 + gsz;
    const char* w1B  = sm + OFF_W1  + arow * 128 + (gsz ^ 64);
    const char* w2A  = sm + OFF_W2  + arow * 128 + gsz;
    const char* w2B  = sm + OFF_W2  + arow * 128 + (gsz ^ 64);
    const char* wihp = sm + OFF_WIH + arow * 16;
    const char* hA   = sm + OFF_H + w * 2048 + bcol * 128 + gsz;
    const char* hB   = sm + OFF_H + w * 2048 + bcol * 128 + (gsz ^ 64);
    const char* aA   = sm + OFF_A + w * 2048 + bcol * 128 + gsz;
    const char* aB   = sm + OFF_A + w * 2048 + bcol * 128 + (gsz ^ 64);
    char* wb0 = sm + OFF_H + w * 2048 + bcol * 128 + (grp & 1) * 8;  // + swz-granule per mt
    const int g1v = grp >> 1;

    const float* bihz = bih + n * 192;
    const float* bhhz = bhh + n * 192;
    const float b3v = b3[n];
    const short8 zfrag = {0, 0, 0, 0, 0, 0, 0, 0};

    f32x4 hp[4];
#pragma unroll
    for (int mt = 0; mt < 4; ++mt) hp[mt] = (f32x4){0.f, 0.f, 0.f, 0.f};

    for (int t = 0; t < 2; ++t) {
        short8 bx = zfrag;
        if (grp == 0)
            bx = *(const short8*)(sm + OFF_X + (t * 128 + w * 16 + bcol) * 16);
        short8 bh0, bh1;
        if (t == 1) {
            bh0 = *(const short8*)hA;
            bh1 = *(const short8*)hB;
        }
        // ---- GRU gates + cell, per M-tile ----
#pragma unroll
        for (int mt = 0; mt < 4; ++mt) {
            const int ch = mt * 16 + ch0;
            f32x4 aR  = *(const f32x4*)&bihz[ch]      + *(const f32x4*)&bhhz[ch];
            f32x4 aZ  = *(const f32x4*)&bihz[64 + ch] + *(const f32x4*)&bhhz[64 + ch];
            f32x4 aXN = *(const f32x4*)&bihz[128 + ch];
            f32x4 aHN = *(const f32x4*)&bhhz[128 + ch];
            short8 wr = zfrag, wzg = zfrag, wn = zfrag;
            if (grp == 0) {
                wr  = *(const short8*)(wihp + (0 + mt) * 256);
                wzg = *(const short8*)(wihp + (4 + mt) * 256);
                wn  = *(const short8*)(wihp + (8 + mt) * 256);
            }
            aR  = __builtin_amdgcn_mfma_f32_16x16x32_bf16(wr,  bx, aR,  0, 0, 0);
            aZ  = __builtin_amdgcn_mfma_f32_16x16x32_bf16(wzg, bx, aZ,  0, 0, 0);
            aXN = __builtin_amdgcn_mfma_f32_16x16x32_bf16(wn,  bx, aXN, 0, 0, 0);
            if (t == 1) {
                aR  = __builtin_amdgcn_mfma_f32_16x16x32_bf16(
                          *(const short8*)(whhA + (0 + mt) * 2048), bh0, aR, 0, 0, 0);
                aR  = __builtin_amdgcn_mfma_f32_16x16x32_bf16(
                          *(const short8*)(whhB + (0 + mt) * 2048), bh1, aR, 0, 0, 0);
                aZ  = __builtin_amdgcn_mfma_f32_16x16x32_bf16(
                          *(const short8*)(whhA + (4 + mt) * 2048), bh0, aZ, 0, 0, 0);
                aZ  = __builtin_amdgcn_mfma_f32_16x16x32_bf16(
                          *(const short8*)(whhB + (4 + mt) * 2048), bh1, aZ, 0, 0, 0);
                aHN = __builtin_amdgcn_mfma_f32_16x16x32_bf16(
                          *(const short8*)(whhA + (8 + mt) * 2048), bh0, aHN, 0, 0, 0);
                aHN = __builtin_amdgcn_mfma_f32_16x16x32_bf16(
                          *(const short8*)(whhB + (8 + mt) * 2048), bh1, aHN, 0, 0, 0);
            }
            // cell (hold in fp32 regs)
            f32x4 h2;
#pragma unroll
            for (int r = 0; r < 4; ++r) {
                float rg = sigf(aR[r]);
                float zg = sigf(aZ[r]);
                float nn = tanhfast(aXN[r] + rg * aHN[r]);
                h2[r] = nn + zg * (hp[mt][r] - nn);
            }
            hp[mt] = h2;
            char* wmt = wb0 + (((2 * mt + g1v) ^ a7) << 4);
            if (t == 0) {
                uint2 ph; ph.x = pkbf(h2[0], h2[1]); ph.y = pkbf(h2[2], h2[3]);
                *(uint2*)wmt = ph;                      // H tile
            }
            uint2 pa;
            pa.x = pkbf(fmaxf(h2[0], 0.f), fmaxf(h2[1], 0.f));
            pa.y = pkbf(fmaxf(h2[2], 0.f), fmaxf(h2[3], 0.f));
            *(uint2*)(wmt + 16384) = pa;                // A tile (act)
        }
        // ---- MLP layer 1 (reads act, writes m1 back to A tile) ----
        {
            short8 ba0 = *(const short8*)aA;
            short8 ba1 = *(const short8*)aB;
#pragma unroll
            for (int mt = 0; mt < 4; ++mt) {
                f32x4 m1 = *(const f32x4*)&b1[n * 64 + mt * 16 + ch0];
                m1 = __builtin_amdgcn_mfma_f32_16x16x32_bf16(
                         *(const short8*)(w1A + mt * 2048), ba0, m1, 0, 0, 0);
                m1 = __builtin_amdgcn_mfma_f32_16x16x32_bf16(
                         *(const short8*)(w1B + mt * 2048), ba1, m1, 0, 0, 0);
                uint2 pm;
                pm.x = pkbf(fmaxf(m1[0], 0.f), fmaxf(m1[1], 0.f));
                pm.y = pkbf(fmaxf(m1[2], 0.f), fmaxf(m1[3], 0.f));
                *(uint2*)(wb0 + (((2 * mt + g1v) ^ a7) << 4) + 16384) = pm;
            }
        }
        // ---- MLP layer 2 + head ----
        {
            short8 bm0 = *(const short8*)aA;
            short8 bm1 = *(const short8*)aB;
            float part = 0.f;
#pragma unroll
            for (int mt = 0; mt < 4; ++mt) {
                f32x4 m2 = *(const f32x4*)&b2[n * 64 + mt * 16 + ch0];
                m2 = __builtin_amdgcn_mfma_f32_16x16x32_bf16(
                         *(const short8*)(w2A + mt * 2048), bm0, m2, 0, 0, 0);
                m2 = __builtin_amdgcn_mfma_f32_16x16x32_bf16(
                         *(const short8*)(w2B + mt * 2048), bm1, m2, 0, 0, 0);
                f32x4 w3v = *(const f32x4*)&W3[n * 64 + mt * 16 + ch0];
#pragma unroll
                for (int r = 0; r < 4; ++r)
                    part += w3v[r] * fmaxf(m2[r], 0.f);
            }
            part += __shfl_xor(part, 16, 64);
            part += __shfl_xor(part, 32, 64);
            float val = 3.f * (sigf(part + b3v) - 0.5f);
            if (l < 16)
                p_flat[n * 4096 + (chunk * 128 + w * 16 + bcol) * 2 + t] = val;  // (n,b,t)-major
        }
    }
}

// ---------------------------------------------------------------------------
// Critic + p-last gather: grid 512, block 256, wave per batch row.
// Only zone 99 contributes; neighbors {99,89,0,0,98}.
// ---------------------------------------------------------------------------
__global__ __launch_bounds__(256, 2)
void critic_kernel(const float* __restrict__ x, const float* __restrict__ p_flat,
                   const float* __restrict__ lmW1, const float* __restrict__ lmb1,
                   const float* __restrict__ lmW2, const float* __restrict__ lmb2,
                   const float* __restrict__ lmW3, const float* __restrict__ lmb3,
                   const float* __restrict__ scWih, const float* __restrict__ scWhh,
                   const float* __restrict__ scbih, const float* __restrict__ scbhh,
                   const float* __restrict__ scW1, const float* __restrict__ scb1,
                   const float* __restrict__ scW2, const float* __restrict__ scb2,
                   const float* __restrict__ scW3, const float* __restrict__ scb3,
                   float* __restrict__ out)
{
    __shared__ float sxi[4][72];
    __shared__ float shh[4][68];
    __shared__ float sab[4][68];
    __shared__ float sc1[4][68];
    __shared__ float sf1[4][132];

    const int tid = threadIdx.x;
    const int wid = tid >> 6;
    const int lane = tid & 63;
    const int b = blockIdx.x * 4 + wid;

    for (int idx = lane; idx < 72; idx += 64) {
        int t = idx / 36, c = idx - t * 36;
        float v = 0.f;
        if (c < 35) {
            int g = c / 7, e = c - g * 7;
            int z = (g == 0) ? 99 : (g == 1) ? 89 : (g == 4) ? 98 : -1;
            if (z >= 0)
                v = (e < 6) ? x[((size_t)b * 2 + t) * 600 + z * 6 + e]
                            : p_flat[b * 200 + t * 100 + z];
        }
        sxi[wid][idx] = v;
    }
    __syncthreads();

    float cg00 = scbih[lane], cg01 = scbih[lane + 64], cg02 = scbih[lane + 128];
    float cg10 = cg00, cg11 = cg01, cg12 = cg02;
    for (int c = 0; c < 35; ++c) {
        float w0 = scWih[lane * 35 + c];
        float w1 = scWih[(lane + 64) * 35 + c];
        float w2 = scWih[(lane + 128) * 35 + c];
        float x0 = sxi[wid][c], x1 = sxi[wid][36 + c];
        cg00 += w0 * x0; cg01 += w1 * x0; cg02 += w2 * x0;
        cg10 += w0 * x1; cg11 += w1 * x1; cg12 += w2 * x1;
    }
    const float bhr = scbhh[lane], bhz = scbhh[lane + 64], bhn = scbhh[lane + 128];
    float r  = 1.f / (1.f + expf(-(cg00 + bhr)));
    float zg = 1.f / (1.f + expf(-(cg01 + bhz)));
    float nn = tanhf(cg02 + r * bhn);
    float hj = (1.f - zg) * nn;
    shh[wid][lane] = hj;
    __syncthreads();
    float ghr = bhr, ghz = bhz, ghn = bhn;
    for (int kc = 0; kc < 16; ++kc) {
        float4 wr  = *(const float4*)&scWhh[lane * 64 + kc * 4];
        float4 wzv = *(const float4*)&scWhh[(lane + 64) * 64 + kc * 4];
        float4 wn  = *(const float4*)&scWhh[(lane + 128) * 64 + kc * 4];
        float4 hv  = *(const float4*)&shh[wid][kc * 4];
        ghr += wr.x * hv.x + wr.y * hv.y + wr.z * hv.z + wr.w * hv.w;
        ghz += wzv.x * hv.x + wzv.y * hv.y + wzv.z * hv.z + wzv.w * hv.w;
        ghn += wn.x * hv.x + wn.y * hv.y + wn.z * hv.z + wn.w * hv.w;
    }
    r  = 1.f / (1.f + expf(-(cg10 + ghr)));
    zg = 1.f / (1.f + expf(-(cg11 + ghz)));
    nn = tanhf(cg12 + r * ghn);
    hj = (1.f - zg) * nn + zg * hj;
    sab[wid][lane] = fmaxf(hj, 0.f);
    __syncthreads();
    float acc = scb1[lane];
    for (int kc = 0; kc < 16; ++kc) {
        float4 wv = *(const float4*)&scW1[lane * 64 + kc * 4];
        float4 av = *(const float4*)&sab[wid][kc * 4];
        acc += wv.x * av.x + wv.y * av.y + wv.z * av.z + wv.w * av.w;
    }
    sc1[wid][lane] = fmaxf(acc, 0.f);
    __syncthreads();
    float acc2 = scb2[lane];
    for (int kc = 0; kc < 16; ++kc) {
        float4 wv = *(const float4*)&scW2[lane * 64 + kc * 4];
        float4 av = *(const float4*)&sc1[wid][kc * 4];
        acc2 += wv.x * av.x + wv.y * av.y + wv.z * av.z + wv.w * av.w;
    }
    float qpart = scW3[lane] * fmaxf(acc2, 0.f);
    float f1a = lmb1[lane], f1c = lmb1[lane + 64];
    for (int c = 0; c < 35; ++c) {
        float xv = sxi[wid][36 + c];
        f1a += lmW1[lane * 35 + c] * xv;
        f1c += lmW1[(lane + 64) * 35 + c] * xv;
    }
    sf1[wid][lane] = fmaxf(f1a, 0.f);
    sf1[wid][lane + 64] = fmaxf(f1c, 0.f);
    __syncthreads();
    float f2a = lmb2[lane], f2c = lmb2[lane + 64];
    for (int kc = 0; kc < 32; ++kc) {
        float4 fv = *(const float4*)&sf1[wid][kc * 4];
        float4 wa = *(const float4*)&lmW2[lane * 128 + kc * 4];
        float4 wc = *(const float4*)&lmW2[(lane + 64) * 128 + kc * 4];
        f2a += wa.x * fv.x + wa.y * fv.y + wa.z * fv.z + wa.w * fv.w;
        f2c += wc.x * fv.x + wc.y * fv.y + wc.z * fv.z + wc.w * fv.w;
    }
    float fpart = lmW3[lane] * fmaxf(f2a, 0.f) + lmW3[lane + 64] * fmaxf(f2c, 0.f);

    float tot = qpart + fpart;
    for (int m = 32; m > 0; m >>= 1) tot += __shfl_xor(tot, m, 64);
    if (lane == 0) out[204800 + b] = tot + scb3[0] + lmb3[0];

    for (int l2 = lane; l2 < 100; l2 += 64)
        out[b * 100 + l2] = p_flat[b * 200 + 100 + l2];
}

extern "C" void kernel_launch(void* const* d_in, const int* in_sizes, int n_in,
                              void* d_out, int out_size, void* d_ws, size_t ws_size,
                              hipStream_t stream) {
    const float* x     = (const float*)d_in[0];
    const float* aWih  = (const float*)d_in[1];
    const float* aWhh  = (const float*)d_in[2];
    const float* abih  = (const float*)d_in[3];
    const float* abhh  = (const float*)d_in[4];
    const float* aW1   = (const float*)d_in[5];
    const float* ab1   = (const float*)d_in[6];
    const float* aW2   = (const float*)d_in[7];
    const float* ab2   = (const float*)d_in[8];
    const float* aW3   = (const float*)d_in[9];
    const float* ab3   = (const float*)d_in[10];
    const float* lmW1  = (const float*)d_in[11];
    const float* lmb1  = (const float*)d_in[12];
    const float* lmW2  = (const float*)d_in[13];
    const float* lmb2  = (const float*)d_in[14];
    const float* lmW3  = (const float*)d_in[15];
    const float* lmb3  = (const float*)d_in[16];
    const float* scWih = (const float*)d_in[17];
    const float* scWhh = (const float*)d_in[18];
    const float* scbih = (const float*)d_in[19];
    const float* scbhh = (const float*)d_in[20];
    const float* scW1  = (const float*)d_in[21];
    const float* scb1  = (const float*)d_in[22];
    const float* scW2  = (const float*)d_in[23];
    const float* scb2  = (const float*)d_in[24];
    const float* scW3  = (const float*)d_in[25];
    const float* scb3  = (const float*)d_in[26];
    float* out = (float*)d_out;
    float* p_flat = (float*)d_ws;   // 409600 f32 = 1.6 MB

    hipFuncSetAttribute((const void*)actor_kernel,
                        hipFuncAttributeMaxDynamicSharedMemorySize, LDS_TOTAL);

    actor_kernel<<<dim3(1600), 512, LDS_TOTAL, stream>>>(
        x, aWih, aWhh, abih, abhh, aW1, ab1, aW2, ab2, aW3, ab3, p_flat);

    critic_kernel<<<dim3(512), 256, 0, stream>>>(
        x, p_flat, lmW1, lmb1, lmW2, lmb2, lmW3, lmb3,
        scWih, scWhh, scbih, scbhh, scW1, scb1, scW2, scb2, scW3, scb3, out);
}

// Round 10
// 96.054 us; speedup vs baseline: 2.1477x; 1.1583x over previous
//
#include <hip/hip_runtime.h>
#include <hip/hip_bf16.h>

typedef __attribute__((ext_vector_type(8))) short short8;
typedef __attribute__((ext_vector_type(4))) float f32x4;

// ---- ws: p_flat (409600 f32) then per-zone pre-swizzled bf16 slab ----
// slab (bytes, per zone, = LDS image [0,44032)):
//   Wih [192][16B] linear @0 (3072); Whh swz @3072 (24576);
//   W1 swz @27648 (8192); W2 swz @35840 (8192).  SLAB = 44032.
// swz: byte(row, pair j) = row*128 + ((j*4) ^ ((row&7)<<4))
#define SLAB 44032
#define WS_W_OFF 1638400

// ---- actor LDS (bytes): [0,44032) weights image; X; H; A. total 80896 ----
#define OFF_X 44032      // [2t][128b][16B] = 4096
#define OFF_H 48128      // [4w][32b][128B swz] = 16384
#define OFF_A 64512      // 16384 -> 80896
#define LDS_TOTAL 80896

__device__ __forceinline__ unsigned pkbf(float a, float b) {
    __hip_bfloat162 h = __float22bfloat162_rn(make_float2(a, b));  // v_cvt_pk_bf16_f32
    return *reinterpret_cast<unsigned*>(&h);
}
__device__ __forceinline__ float sigf(float x) {
    return __builtin_amdgcn_rcpf(1.f + __builtin_amdgcn_exp2f(-1.4426950408889634f * x));
}
__device__ __forceinline__ float tanhfast(float y) {
    return 1.f - 2.f * __builtin_amdgcn_rcpf(1.f + __builtin_amdgcn_exp2f(2.8853900817779268f * y));
}
__device__ __forceinline__ void g2l16(const void* g, void* l) {
    __builtin_amdgcn_global_load_lds(
        (const __attribute__((address_space(1))) void*)g,
        (__attribute__((address_space(3))) void*)l, 16, 0, 0);
}

// ---------------------------------------------------------------------------
// Pre-pass: build pre-swizzled bf16 slabs (exact LDS image) in ws.
// One thread per packed dword: 11008 dwords/zone.
// ---------------------------------------------------------------------------
__global__ __launch_bounds__(256)
void convert_kernel(const float* __restrict__ Wih, const float* __restrict__ Whh,
                    const float* __restrict__ W1, const float* __restrict__ W2,
                    char* __restrict__ slab)
{
    int idx = blockIdx.x * 256 + threadIdx.x;
    if (idx >= 100 * 11008) return;
    int n = idx / 11008;
    int i = idx - n * 11008;
    char* zs = slab + (size_t)n * SLAB;
    if (i < 768) {                                   // Wih linear [192][16B]
        int row = i >> 2, j = i & 3;
        const float* g = Wih + n * 1152 + row * 6;
        float a = (2 * j < 6) ? g[2 * j] : 0.f;
        float b = (2 * j + 1 < 6) ? g[2 * j + 1] : 0.f;
        *(unsigned*)(zs + row * 16 + j * 4) = pkbf(a, b);
    } else if (i < 6912) {                           // Whh swz
        int k = i - 768, row = k >> 5, j = k & 31;
        float2 v = *(const float2*)(Whh + n * 12288 + row * 64 + j * 2);
        *(unsigned*)(zs + 3072 + row * 128 + ((j * 4) ^ ((row & 7) << 4))) = pkbf(v.x, v.y);
    } else if (i < 8960) {                           // W1 swz
        int k = i - 6912, row = k >> 5, j = k & 31;
        float2 v = *(const float2*)(W1 + n * 4096 + row * 64 + j * 2);
        *(unsigned*)(zs + 27648 + row * 128 + ((j * 4) ^ ((row & 7) << 4))) = pkbf(v.x, v.y);
    } else {                                         // W2 swz
        int k = i - 8960, row = k >> 5, j = k & 31;
        float2 v = *(const float2*)(W2 + n * 4096 + row * 64 + j * 2);
        *(unsigned*)(zs + 35840 + row * 128 + ((j * 4) ^ ((row & 7) << 4))) = pkbf(v.x, v.y);
    }
}

// ---------------------------------------------------------------------------
// Actor: grid 1600 = 100 zones x 16 chunks(128 batches), block 256 = 4 waves.
// Wave owns 32 batches = 2 N-subtiles of 16 (2 independent ILP streams).
// Weights arrive via global_load_lds from the pre-swizzled slab (LDS dest
// linear = slab image). 80896 B LDS -> 2 blocks/CU. One __syncthreads.
// C/D: col=lane&15 (batch), row=(lane>>4)*4+reg (channel)  [m89-verified].
// p written ONLY to p_flat in (n,b,t)-major order; the p[:, -1] output is a
// FLAT-REINTERPRETED gather (p[b,1,nn] = flat[b*200+100+nn]) done in critic.
// ---------------------------------------------------------------------------
__global__ __launch_bounds__(256, 2)
void actor_kernel(const float* __restrict__ x, const char* __restrict__ slab,
                  const float* __restrict__ bih, const float* __restrict__ bhh,
                  const float* __restrict__ b1, const float* __restrict__ b2,
                  const float* __restrict__ W3, const float* __restrict__ b3,
                  float* __restrict__ p_flat)
{
    extern __shared__ char sm[];
    const int tid   = threadIdx.x;
    const int n     = blockIdx.x >> 4;
    const int chunk = blockIdx.x & 15;
    const int w     = tid >> 6;
    const int l     = tid & 63;
    const int bcol  = l & 15;
    const int grp   = l >> 4;
    const int a7    = bcol & 7;
    const int ch0   = grp * 4;

    // ---- staging: weights via async global->LDS (43 KB, linear image) ----
    {
        const char* gz = slab + (size_t)n * SLAB;
        for (int i = w; i < 43; i += 4)
            g2l16(gz + i * 1024 + l * 16, sm + i * 1024);
        // x: 256 rows (t,b), 6 f32 -> 8 bf16
        int t = tid >> 7, b = tid & 127;
        const float* xr = x + (size_t)(chunk * 128 + b) * 1200 + t * 600 + n * 6;
        uint4 pk;
        pk.x = pkbf(xr[0], xr[1]);
        pk.y = pkbf(xr[2], xr[3]);
        pk.z = pkbf(xr[4], xr[5]);
        pk.w = 0u;
        *(uint4*)(sm + OFF_X + (t * 128 + b) * 16) = pk;
    }
    __syncthreads();   // drains vmcnt (global_load_lds) + lgkmcnt

    // ---- swizzled bases ----
    const int gsz = (grp ^ a7) << 4;
    const char* wihp = sm + bcol * 16;                       // + tile*256
    const char* whhA = sm + 3072  + bcol * 128 + gsz;        // + gtile*2048
    const char* whhB = sm + 3072  + bcol * 128 + (gsz ^ 64);
    const char* w1A  = sm + 27648 + bcol * 128 + gsz;
    const char* w1B  = sm + 27648 + bcol * 128 + (gsz ^ 64);
    const char* w2A  = sm + 35840 + bcol * 128 + gsz;
    const char* w2B  = sm + 35840 + bcol * 128 + (gsz ^ 64);
    char* hTile = sm + OFF_H + w * 4096;                     // [32b][128B]
    char* aTile = sm + OFF_A + w * 4096;
    const int wgr = (grp & 1) * 8;
    const int g1v = grp >> 1;

    // ---- hoisted biases (persistent regs; cap is 256 VGPR) ----
    const float* bihz = bih + n * 192;
    const float* bhhz = bhh + n * 192;
    f32x4 bRi[4], bZi[4], bXNi[4], bHNi[4];
#pragma unroll
    for (int mt = 0; mt < 4; ++mt) {
        const int ch = mt * 16 + ch0;
        bRi[mt]  = *(const f32x4*)&bihz[ch]      + *(const f32x4*)&bhhz[ch];
        bZi[mt]  = *(const f32x4*)&bihz[64 + ch] + *(const f32x4*)&bhhz[64 + ch];
        bXNi[mt] = *(const f32x4*)&bihz[128 + ch];
        bHNi[mt] = *(const f32x4*)&bhhz[128 + ch];
    }
    const float b3v = b3[n];
    const short8 zfrag = {0, 0, 0, 0, 0, 0, 0, 0};

    f32x4 hp[2][4];
#pragma unroll
    for (int nt = 0; nt < 2; ++nt)
#pragma unroll
        for (int mt = 0; mt < 4; ++mt) hp[nt][mt] = (f32x4){0.f, 0.f, 0.f, 0.f};

    for (int t = 0; t < 2; ++t) {
        short8 bxv[2] = {zfrag, zfrag};
        if (grp == 0) {
            bxv[0] = *(const short8*)(sm + OFF_X + (t * 128 + w * 32 + bcol) * 16);
            bxv[1] = *(const short8*)(sm + OFF_X + (t * 128 + w * 32 + 16 + bcol) * 16);
        }
        short8 bh0v[2], bh1v[2];
        if (t == 1) {
#pragma unroll
            for (int nt = 0; nt < 2; ++nt) {
                bh0v[nt] = *(const short8*)(hTile + (nt * 16 + bcol) * 128 + gsz);
                bh1v[nt] = *(const short8*)(hTile + (nt * 16 + bcol) * 128 + (gsz ^ 64));
            }
        }
        // ---- GRU gates + cell, per M-tile, 2 subtile streams ----
#pragma unroll
        for (int mt = 0; mt < 4; ++mt) {
            f32x4 aR[2], aZ[2], aXN[2], aHN[2];
#pragma unroll
            for (int nt = 0; nt < 2; ++nt) {
                aR[nt] = bRi[mt]; aZ[nt] = bZi[mt]; aXN[nt] = bXNi[mt]; aHN[nt] = bHNi[mt];
            }
            short8 wr = zfrag, wzg = zfrag, wn = zfrag;
            if (grp == 0) {
                wr  = *(const short8*)(wihp + (0 + mt) * 256);
                wzg = *(const short8*)(wihp + (4 + mt) * 256);
                wn  = *(const short8*)(wihp + (8 + mt) * 256);
            }
#pragma unroll
            for (int nt = 0; nt < 2; ++nt) {
                aR[nt]  = __builtin_amdgcn_mfma_f32_16x16x32_bf16(wr,  bxv[nt], aR[nt],  0, 0, 0);
                aZ[nt]  = __builtin_amdgcn_mfma_f32_16x16x32_bf16(wzg, bxv[nt], aZ[nt],  0, 0, 0);
                aXN[nt] = __builtin_amdgcn_mfma_f32_16x16x32_bf16(wn,  bxv[nt], aXN[nt], 0, 0, 0);
            }
            if (t == 1) {
                short8 r0 = *(const short8*)(whhA + (0 + mt) * 2048);
                short8 r1 = *(const short8*)(whhB + (0 + mt) * 2048);
                short8 z0 = *(const short8*)(whhA + (4 + mt) * 2048);
                short8 z1 = *(const short8*)(whhB + (4 + mt) * 2048);
                short8 n0 = *(const short8*)(whhA + (8 + mt) * 2048);
                short8 n1 = *(const short8*)(whhB + (8 + mt) * 2048);
#pragma unroll
                for (int nt = 0; nt < 2; ++nt) {
                    aR[nt]  = __builtin_amdgcn_mfma_f32_16x16x32_bf16(r0, bh0v[nt], aR[nt],  0, 0, 0);
                    aR[nt]  = __builtin_amdgcn_mfma_f32_16x16x32_bf16(r1, bh1v[nt], aR[nt],  0, 0, 0);
                    aZ[nt]  = __builtin_amdgcn_mfma_f32_16x16x32_bf16(z0, bh0v[nt], aZ[nt],  0, 0, 0);
                    aZ[nt]  = __builtin_amdgcn_mfma_f32_16x16x32_bf16(z1, bh1v[nt], aZ[nt],  0, 0, 0);
                    aHN[nt] = __builtin_amdgcn_mfma_f32_16x16x32_bf16(n0, bh0v[nt], aHN[nt], 0, 0, 0);
                    aHN[nt] = __builtin_amdgcn_mfma_f32_16x16x32_bf16(n1, bh1v[nt], aHN[nt], 0, 0, 0);
                }
            }
#pragma unroll
            for (int nt = 0; nt < 2; ++nt) {
                f32x4 h2;
#pragma unroll
                for (int r = 0; r < 4; ++r) {
                    float rg = sigf(aR[nt][r]);
                    float zg = sigf(aZ[nt][r]);
                    float nn = tanhfast(aXN[nt][r] + rg * aHN[nt][r]);
                    h2[r] = nn + zg * (hp[nt][mt][r] - nn);
                }
                hp[nt][mt] = h2;
                char* wmt = hTile + nt * 2048 + bcol * 128 + wgr + (((2 * mt + g1v) ^ a7) << 4);
                if (t == 0) {
                    uint2 ph; ph.x = pkbf(h2[0], h2[1]); ph.y = pkbf(h2[2], h2[3]);
                    *(uint2*)wmt = ph;
                }
                uint2 pa;
                pa.x = pkbf(fmaxf(h2[0], 0.f), fmaxf(h2[1], 0.f));
                pa.y = pkbf(fmaxf(h2[2], 0.f), fmaxf(h2[3], 0.f));
                *(uint2*)(wmt + 16384) = pa;
            }
        }
        // ---- MLP layer 1 ----
        {
            short8 ba0[2], ba1[2];
#pragma unroll
            for (int nt = 0; nt < 2; ++nt) {
                ba0[nt] = *(const short8*)(aTile + (nt * 16 + bcol) * 128 + gsz);
                ba1[nt] = *(const short8*)(aTile + (nt * 16 + bcol) * 128 + (gsz ^ 64));
            }
#pragma unroll
            for (int mt = 0; mt < 4; ++mt) {
                short8 wa  = *(const short8*)(w1A + mt * 2048);
                short8 wbv = *(const short8*)(w1B + mt * 2048);
                f32x4 bmv = *(const f32x4*)&b1[n * 64 + mt * 16 + ch0];
#pragma unroll
                for (int nt = 0; nt < 2; ++nt) {
                    f32x4 m1 = bmv;
                    m1 = __builtin_amdgcn_mfma_f32_16x16x32_bf16(wa,  ba0[nt], m1, 0, 0, 0);
                    m1 = __builtin_amdgcn_mfma_f32_16x16x32_bf16(wbv, ba1[nt], m1, 0, 0, 0);
                    uint2 pm;
                    pm.x = pkbf(fmaxf(m1[0], 0.f), fmaxf(m1[1], 0.f));
                    pm.y = pkbf(fmaxf(m1[2], 0.f), fmaxf(m1[3], 0.f));
                    *(uint2*)(aTile + nt * 2048 + bcol * 128 + wgr + (((2 * mt + g1v) ^ a7) << 4)) = pm;
                }
            }
        }
        // ---- MLP layer 2 + head ----
        {
            short8 bm0[2], bm1[2];
#pragma unroll
            for (int nt = 0; nt < 2; ++nt) {
                bm0[nt] = *(const short8*)(aTile + (nt * 16 + bcol) * 128 + gsz);
                bm1[nt] = *(const short8*)(aTile + (nt * 16 + bcol) * 128 + (gsz ^ 64));
            }
            float part[2] = {0.f, 0.f};
#pragma unroll
            for (int mt = 0; mt < 4; ++mt) {
                short8 wa  = *(const short8*)(w2A + mt * 2048);
                short8 wbv = *(const short8*)(w2B + mt * 2048);
                f32x4 bmv = *(const f32x4*)&b2[n * 64 + mt * 16 + ch0];
                f32x4 w3v = *(const f32x4*)&W3[n * 64 + mt * 16 + ch0];
#pragma unroll
                for (int nt = 0; nt < 2; ++nt) {
                    f32x4 m2 = bmv;
                    m2 = __builtin_amdgcn_mfma_f32_16x16x32_bf16(wa,  bm0[nt], m2, 0, 0, 0);
                    m2 = __builtin_amdgcn_mfma_f32_16x16x32_bf16(wbv, bm1[nt], m2, 0, 0, 0);
#pragma unroll
                    for (int r = 0; r < 4; ++r)
                        part[nt] += w3v[r] * fmaxf(m2[r], 0.f);
                }
            }
#pragma unroll
            for (int nt = 0; nt < 2; ++nt) {
                part[nt] += __shfl_xor(part[nt], 16, 64);
                part[nt] += __shfl_xor(part[nt], 32, 64);
            }
            if (l < 16) {
#pragma unroll
                for (int nt = 0; nt < 2; ++nt) {
                    int bg = chunk * 128 + w * 32 + nt * 16 + bcol;
                    float val = 3.f * (sigf(part[nt] + b3v) - 0.5f);
                    p_flat[n * 4096 + bg * 2 + t] = val;     // (n,b,t)-major
                }
            }
        }
    }
}

// ---------------------------------------------------------------------------
// Critic + p-last gather (PROVEN form): grid 512, block 256, wave/batch row.
// Only zone 99 contributes; neighbors {99,89,0,0,98}.
// p[b,t,nn] = p_flat_FLAT[b*200 + t*100 + nn]  (flat reinterpretation!).
// ---------------------------------------------------------------------------
__global__ __launch_bounds__(256, 2)
void critic_kernel(const float* __restrict__ x, const float* __restrict__ p_flat,
                   const float* __restrict__ lmW1, const float* __restrict__ lmb1,
                   const float* __restrict__ lmW2, const float* __restrict__ lmb2,
                   const float* __restrict__ lmW3, const float* __restrict__ lmb3,
                   const float* __restrict__ scWih, const float* __restrict__ scWhh,
                   const float* __restrict__ scbih, const float* __restrict__ scbhh,
                   const float* __restrict__ scW1, const float* __restrict__ scb1,
                   const float* __restrict__ scW2, const float* __restrict__ scb2,
                   const float* __restrict__ scW3, const float* __restrict__ scb3,
                   float* __restrict__ out)
{
    __shared__ float sxi[4][72];
    __shared__ float shh[4][68];
    __shared__ float sab[4][68];
    __shared__ float sc1[4][68];
    __shared__ float sf1[4][132];

    const int tid = threadIdx.x;
    const int wid = tid >> 6;
    const int lane = tid & 63;
    const int b = blockIdx.x * 4 + wid;

    for (int idx = lane; idx < 72; idx += 64) {
        int t = idx / 36, c = idx - t * 36;
        float v = 0.f;
        if (c < 35) {
            int g = c / 7, e = c - g * 7;
            int z = (g == 0) ? 99 : (g == 1) ? 89 : (g == 4) ? 98 : -1;
            if (z >= 0)
                v = (e < 6) ? x[((size_t)b * 2 + t) * 600 + z * 6 + e]
                            : p_flat[b * 200 + t * 100 + z];
        }
        sxi[wid][idx] = v;
    }
    __syncthreads();

    float cg00 = scbih[lane], cg01 = scbih[lane + 64], cg02 = scbih[lane + 128];
    float cg10 = cg00, cg11 = cg01, cg12 = cg02;
    for (int c = 0; c < 35; ++c) {
        float w0 = scWih[lane * 35 + c];
        float w1 = scWih[(lane + 64) * 35 + c];
        float w2 = scWih[(lane + 128) * 35 + c];
        float x0 = sxi[wid][c], x1 = sxi[wid][36 + c];
        cg00 += w0 * x0; cg01 += w1 * x0; cg02 += w2 * x0;
        cg10 += w0 * x1; cg11 += w1 * x1; cg12 += w2 * x1;
    }
    const float bhr = scbhh[lane], bhz = scbhh[lane + 64], bhn = scbhh[lane + 128];
    float r  = 1.f / (1.f + expf(-(cg00 + bhr)));
    float zg = 1.f / (1.f + expf(-(cg01 + bhz)));
    float nn = tanhf(cg02 + r * bhn);
    float hj = (1.f - zg) * nn;
    shh[wid][lane] = hj;
    __syncthreads();
    float ghr = bhr, ghz = bhz, ghn = bhn;
    for (int kc = 0; kc < 16; ++kc) {
        float4 wr  = *(const float4*)&scWhh[lane * 64 + kc * 4];
        float4 wzv = *(const float4*)&scWhh[(lane + 64) * 64 + kc * 4];
        float4 wn  = *(const float4*)&scWhh[(lane + 128) * 64 + kc * 4];
        float4 hv  = *(const float4*)&shh[wid][kc * 4];
        ghr += wr.x * hv.x + wr.y * hv.y + wr.z * hv.z + wr.w * hv.w;
        ghz += wzv.x * hv.x + wzv.y * hv.y + wzv.z * hv.z + wzv.w * hv.w;
        ghn += wn.x * hv.x + wn.y * hv.y + wn.z * hv.z + wn.w * hv.w;
    }
    r  = 1.f / (1.f + expf(-(cg10 + ghr)));
    zg = 1.f / (1.f + expf(-(cg11 + ghz)));
    nn = tanhf(cg12 + r * ghn);
    hj = (1.f - zg) * nn + zg * hj;
    sab[wid][lane] = fmaxf(hj, 0.f);
    __syncthreads();
    float acc = scb1[lane];
    for (int kc = 0; kc < 16; ++kc) {
        float4 wv = *(const float4*)&scW1[lane * 64 + kc * 4];
        float4 av = *(const float4*)&sab[wid][kc * 4];
        acc += wv.x * av.x + wv.y * av.y + wv.z * av.z + wv.w * av.w;
    }
    sc1[wid][lane] = fmaxf(acc, 0.f);
    __syncthreads();
    float acc2 = scb2[lane];
    for (int kc = 0; kc < 16; ++kc) {
        float4 wv = *(const float4*)&scW2[lane * 64 + kc * 4];
        float4 av = *(const float4*)&sc1[wid][kc * 4];
        acc2 += wv.x * av.x + wv.y * av.y + wv.z * av.z + wv.w * av.w;
    }
    float qpart = scW3[lane] * fmaxf(acc2, 0.f);
    float f1a = lmb1[lane], f1c = lmb1[lane + 64];
    for (int c = 0; c < 35; ++c) {
        float xv = sxi[wid][36 + c];
        f1a += lmW1[lane * 35 + c] * xv;
        f1c += lmW1[(lane + 64) * 35 + c] * xv;
    }
    sf1[wid][lane] = fmaxf(f1a, 0.f);
    sf1[wid][lane + 64] = fmaxf(f1c, 0.f);
    __syncthreads();
    float f2a = lmb2[lane], f2c = lmb2[lane + 64];
    for (int kc = 0; kc < 32; ++kc) {
        float4 fv = *(const float4*)&sf1[wid][kc * 4];
        float4 wa = *(const float4*)&lmW2[lane * 128 + kc * 4];
        float4 wc = *(const float4*)&lmW2[(lane + 64) * 128 + kc * 4];
        f2a += wa.x * fv.x + wa.y * fv.y + wa.z * fv.z + wa.w * fv.w;
        f2c += wc.x * fv.x + wc.y * fv.y + wc.z * fv.z + wc.w * fv.w;
    }
    float fpart = lmW3[lane] * fmaxf(f2a, 0.f) + lmW3[lane + 64] * fmaxf(f2c, 0.f);

    float tot = qpart + fpart;
    for (int m = 32; m > 0; m >>= 1) tot += __shfl_xor(tot, m, 64);
    if (lane == 0) out[204800 + b] = tot + scb3[0] + lmb3[0];

    // p[:, -1] gather: out[b*100 + l2] = flat[b*200 + 100 + l2]
    for (int l2 = lane; l2 < 100; l2 += 64)
        out[b * 100 + l2] = p_flat[b * 200 + 100 + l2];
}

extern "C" void kernel_launch(void* const* d_in, const int* in_sizes, int n_in,
                              void* d_out, int out_size, void* d_ws, size_t ws_size,
                              hipStream_t stream) {
    const float* x     = (const float*)d_in[0];
    const float* aWih  = (const float*)d_in[1];
    const float* aWhh  = (const float*)d_in[2];
    const float* abih  = (const float*)d_in[3];
    const float* abhh  = (const float*)d_in[4];
    const float* aW1   = (const float*)d_in[5];
    const float* ab1   = (const float*)d_in[6];
    const float* aW2   = (const float*)d_in[7];
    const float* ab2   = (const float*)d_in[8];
    const float* aW3   = (const float*)d_in[9];
    const float* ab3   = (const float*)d_in[10];
    const float* lmW1  = (const float*)d_in[11];
    const float* lmb1  = (const float*)d_in[12];
    const float* lmW2  = (const float*)d_in[13];
    const float* lmb2  = (const float*)d_in[14];
    const float* lmW3  = (const float*)d_in[15];
    const float* lmb3  = (const float*)d_in[16];
    const float* scWih = (const float*)d_in[17];
    const float* scWhh = (const float*)d_in[18];
    const float* scbih = (const float*)d_in[19];
    const float* scbhh = (const float*)d_in[20];
    const float* scW1  = (const float*)d_in[21];
    const float* scb1  = (const float*)d_in[22];
    const float* scW2  = (const float*)d_in[23];
    const float* scb2  = (const float*)d_in[24];
    const float* scW3  = (const float*)d_in[25];
    const float* scb3  = (const float*)d_in[26];
    float* out = (float*)d_out;
    float* p_flat = (float*)d_ws;                        // 1.6 MB
    char* slab = (char*)d_ws + WS_W_OFF;                 // 4.4 MB

    hipFuncSetAttribute((const void*)actor_kernel,
                        hipFuncAttributeMaxDynamicSharedMemorySize, LDS_TOTAL);

    convert_kernel<<<dim3((100 * 11008 + 255) / 256), 256, 0, stream>>>(
        aWih, aWhh, aW1, aW2, slab);

    actor_kernel<<<dim3(1600), 256, LDS_TOTAL, stream>>>(
        x, slab, abih, abhh, ab1, ab2, aW3, ab3, p_flat);

    critic_kernel<<<dim3(512), 256, 0, stream>>>(
        x, p_flat, lmW1, lmb1, lmW2, lmb2, lmW3, lmb3,
        scWih, scWhh, scbih, scbhh, scW1, scb1, scW2, scb2, scW3, scb3, out);
}